// Round 6
// baseline (226.070 us; speedup 1.0000x reference)
//
#include <hip/hip_runtime.h>
#include <math.h>

// ---------------- problem constants ----------------
constexpr int N_CPGS = 20000;
constexpr int NF     = 10001;      // N/2+1
constexpr int BZ     = 4;
constexpr int NEDGE  = 320000;
constexpr int KPAD   = 10240;      // padded freq count (40 blocks * 256)
// FFT decomposition: n = n1 + 200*n2, n1 in [0,200), n2 in [0,100)
constexpr int FN1    = 200;
constexpr int FN2    = 100;
constexpr int NS2    = 8;          // stage-2 n1-chunks (25 each)
constexpr int TILES  = (N_CPGS + 63) / 64;   // 313
constexpr int HB     = NEDGE / 256;          // 1250 hist/scatter blocks
constexpr int GATB   = 1024;                 // GAT blocks (4096 waves)

// ---------------- workspace layout (float offsets) ----------------
constexpr size_t W_XMEAN   = 0;        // 4
constexpr size_t W_SMSTAT  = 64;       // 2
constexpr size_t W_NORMSQ  = 128;      // 4   [zeroed in k_pre]
constexpr size_t W_H0SUM   = 192;      // 256 [zeroed in k_pre]
constexpr size_t W_GATMEAN = 448;      // 256 [zeroed in k_pre]
constexpr size_t W_PREP    = 704;      // 8 (mw, mb, A, C, D)
constexpr size_t W_D       = 768;      // 3*128*4
constexpr size_t W_MAG     = 2304;     // BZ*NF = 40004
constexpr size_t W_SSRC    = 42368;    // float[(n*4+b)*4+h] = 320000
constexpr size_t W_SDST    = 362368;   // 320000
constexpr size_t W_H       = 682368;   // bf16[(n*4+b)*64+f] = 5.12MB
constexpr size_t W_Y       = 5802368;  // float2[(n1*100+k2)*4+b] = 160000 floats
constexpr size_t W_P2      = 5962368;  // NS2*KPAD*8 = 655360 floats
constexpr size_t W_COUNTS  = 9079168;  // int 20000 [zeroed in k_pre]
constexpr size_t W_OFFS    = 9099168;  // int 20001
constexpr size_t W_CURSOR  = 9119232;  // int 20000
constexpr size_t W_SORTSRC = 9139232;  // int 320000
// end: 9459232 floats = 37,836,928 bytes

#define DEVFN static __device__ __forceinline__

// Fast gelu: A&S 7.1.26 erf, |abs err| <= 1.5e-7.
DEVFN float gelu_f(float v) {
    float ax = fabsf(v) * 0.70710678118654752440f;
    float t = 1.0f / fmaf(0.3275911f, ax, 1.0f);
    float p = fmaf(t, 1.061405429f, -1.453152027f);
    p = fmaf(p, t, 1.421413741f);
    p = fmaf(p, t, -0.284496736f);
    p = fmaf(p, t, 0.254829592f);
    p = p * t;
    float e = __expf(-ax * ax);
    float er = copysignf(fmaf(-p, e, 1.0f), v);
    return 0.5f * v * (1.0f + er);
}

DEVFN float wred_sum(float v) {
    #pragma unroll
    for (int m = 32; m; m >>= 1) v += __shfl_xor(v, m);
    return v;
}

DEVFN unsigned int bfr(float f) {            // fp32 -> bf16 bits, RNE
    unsigned int u = __float_as_uint(f);
    return (u + 0x7fffu + ((u >> 16) & 1u)) >> 16;
}
DEVFN float bf2f(unsigned short v) { return __uint_as_float(((unsigned int)v) << 16); }

// ================= L1: k_pre =================
__global__ void k_pre(const float* __restrict__ x, const float* __restrict__ ge_w,
                      const float* __restrict__ ge_b, const float* __restrict__ fw,
                      float* __restrict__ ws) {
    int bb = blockIdx.x, t = threadIdx.x;
    __shared__ float sd[256];
    if (bb < 4) {
        const float4* x4 = (const float4*)(x + (size_t)bb * N_CPGS);
        float s = 0.f;
        for (int i = t; i < N_CPGS / 4; i += 256) {
            float4 v = x4[i];
            s += (v.x + v.y) + (v.z + v.w);
        }
        sd[t] = s; __syncthreads();
        for (int o = 128; o; o >>= 1) { if (t < o) sd[t] += sd[t + o]; __syncthreads(); }
        if (t == 0) ws[W_XMEAN + bb] = sd[0] * (1.0f / N_CPGS);
    } else if (bb == 4) {
        for (int i = t; i < (int)(W_PREP - W_NORMSQ); i += 256) ws[W_NORMSQ + i] = 0.f;
        if (t < 64) {
            float w = ge_w[t], b = ge_b[t];
            float mw = wred_sum(w) * (1.f / 64.f);
            float mb = wred_sum(b) * (1.f / 64.f);
            float wc = w - mw, bc = b - mb;
            float A = wred_sum(wc * wc) * (1.f / 64.f);
            float C = wred_sum(wc * bc) * (1.f / 64.f);
            float D = wred_sum(bc * bc) * (1.f / 64.f);
            if (t == 0) { float* p = ws + W_PREP; p[0] = mw; p[1] = mb; p[2] = A; p[3] = C; p[4] = D; }
        }
    } else if (bb == 5) {
        float mx = -1e30f;
        for (int i = t; i < NF; i += 256) mx = fmaxf(mx, fw[i]);
        sd[t] = mx; __syncthreads();
        for (int o = 128; o; o >>= 1) { if (t < o) sd[t] = fmaxf(sd[t], sd[t + o]); __syncthreads(); }
        mx = sd[0]; __syncthreads();
        float s = 0.f;
        for (int i = t; i < NF; i += 256) s += expf(fw[i] - mx);
        sd[t] = s; __syncthreads();
        for (int o = 128; o; o >>= 1) { if (t < o) sd[t] += sd[t + o]; __syncthreads(); }
        if (t == 0) { ws[W_SMSTAT] = mx; ws[W_SMSTAT + 1] = sd[0]; }
    } else {
        int base = (bb - 6) * 1000;
        int* cnt = (int*)(ws + W_COUNTS);
        for (int i = t; i < 1000; i += 256) cnt[base + i] = 0;
    }
}

// ================= L2: k_node — node tiles + edge histogram + FFT stage 1 =================
__global__ __launch_bounds__(256) void k_node(
    const float* __restrict__ x, const float* __restrict__ ge_w, const float* __restrict__ ge_b,
    const float* __restrict__ ge_g, const float* __restrict__ ge_beta,
    const float* __restrict__ gat_w, const float* __restrict__ gat_attn,
    const int* __restrict__ ei, float* __restrict__ ws)
{
    int t = threadIdx.x;
    int nb = blockIdx.x;
    if (nb >= 4 * TILES) {
        int r = nb - 4 * TILES;
        if (r < HB) {                                  // fused edge histogram
            int e = r * 256 + t;
            if (e < NEDGE) atomicAdd((int*)(ws + W_COUNTS) + ei[NEDGE + e], 1);
        } else {                                       // FFT stage 1
            int fb = r - HB;                           // 0..399
            int b = fb / 100;
            int n1base = (fb % 100) * 2;
            int n1l = t >> 7, k2 = t & 127;
            __shared__ float xs[2][100];
            float xm = ws[W_XMEAN + b];
            for (int i = t; i < 200; i += 256) {
                int nl = (i >= 100) ? 1 : 0, n2 = (i >= 100) ? i - 100 : i;
                xs[nl][n2] = x[(size_t)b * N_CPGS + n1base + nl + 200 * n2] - xm;
            }
            __syncthreads();
            int k2e = (k2 < 100) ? k2 : 0;
            constexpr float T100 = 6.2831853071795864769f / 100.f;
            float dc, dsn;
            { float sn, cn; sincosf(T100 * (float)k2e, &sn, &cn); dc = cn; dsn = -sn; }
            float yr = 0.f, yi = 0.f;
            #pragma unroll
            for (int half = 0; half < 2; ++half) {
                float c, s;
                { int m = (k2e * (half * 50)) % 100; float sn, cn; sincosf(T100 * (float)m, &sn, &cn); c = cn; s = -sn; }
                #pragma unroll 5
                for (int j = 0; j < 50; ++j) {
                    float xv = xs[n1l][half * 50 + j];
                    yr = fmaf(xv, c, yr); yi = fmaf(xv, s, yi);
                    float tc_ = c * dc - s * dsn; s = s * dc + c * dsn; c = tc_;
                }
            }
            if (k2 < 100)
                ((float2*)(ws + W_Y))[((size_t)(n1base + n1l) * FN2 + k2) * 4 + b] = make_float2(yr, yi);
        }
        return;
    }
    int b = nb / TILES;
    int tile = nb % TILES;
    int n0 = tile * 64;

    __shared__ __align__(16) float h0T[64 * 68];   // [feat j][node]
    __shared__ __align__(16) float gwT[64 * 68];   // [j][i] = gat_w[i][j]
    __shared__ float xsv[64], rss[64];

    const float* prep = ws + W_PREP;
    float mw = prep[0], mb = prep[1], A = prep[2], C = prep[3], Dd = prep[4];

    for (int idx = t; idx < 4096; idx += 256) { int i = idx >> 6, j = idx & 63; gwT[j * 68 + i] = gat_w[idx]; }
    if (t < 64) {
        int n = n0 + t;
        float xv = (n < N_CPGS) ? x[(size_t)b * N_CPGS + n] : 0.f;
        xsv[t] = xv;
        float var = xv * xv * A + 2.f * xv * C + Dd;
        rss[t] = 1.0f / sqrtf(var + 1e-5f);
    }
    __syncthreads();

    for (int idx = t; idx < 4096; idx += 256) {
        int j = idx >> 6, nd = idx & 63;
        float h0 = 0.f;
        if (n0 + nd < N_CPGS) {
            float v = (xsv[nd] * (ge_w[j] - mw) + (ge_b[j] - mb)) * rss[nd];
            h0 = gelu_f(v * ge_g[j] + ge_beta[j]);
        }
        h0T[j * 68 + nd] = h0;
    }
    __syncthreads();

    // 64x64 @ 64x64 matmul, 16x16 threads, 4x4 micro-tile
    int tr = t >> 4, tc = t & 15;
    float acc[4][4] = {};
    #pragma unroll 8
    for (int j = 0; j < 64; ++j) {
        const float4 av = *(const float4*)&h0T[j * 68 + (tr << 2)];
        const float4 bv = *(const float4*)&gwT[j * 68 + (tc << 2)];
        #pragma unroll
        for (int u = 0; u < 4; ++u) {
            float a = (u == 0) ? av.x : (u == 1) ? av.y : (u == 2) ? av.z : av.w;
            acc[u][0] = fmaf(a, bv.x, acc[u][0]);
            acc[u][1] = fmaf(a, bv.y, acc[u][1]);
            acc[u][2] = fmaf(a, bv.z, acc[u][2]);
            acc[u][3] = fmaf(a, bv.w, acc[u][3]);
        }
    }
    // h0 feature sums
    if (t < 64) {
        float s = 0.f;
        #pragma unroll 8
        for (int nd = 0; nd < 64; ++nd) s += h0T[t * 68 + nd];
        atomicAdd(ws + W_H0SUM + b * 64 + t, s);
    }
    // h write (bf16, interleaved [n][b][f])
    unsigned short* hbp = (unsigned short*)(ws + W_H);
    #pragma unroll
    for (int u = 0; u < 4; ++u) {
        int n = n0 + tr * 4 + u;
        if (n < N_CPGS) {
            unsigned int lo = bfr(acc[u][0]) | (bfr(acc[u][1]) << 16);
            unsigned int hi = bfr(acc[u][2]) | (bfr(acc[u][3]) << 16);
            *(uint2*)(hbp + ((size_t)n * 4 + b) * 64 + tc * 4) = make_uint2(lo, hi);
        }
    }
    // attention scores straight from registers:
    // thread owns h[n=tr*4+u][i=tc*4+kk], head hh=tc>>2, d=(tc&3)*4+kk
    {
        int hh = tc >> 2;
        float ps[4], pd[4];
        #pragma unroll
        for (int u = 0; u < 4; ++u) {
            float s = 0.f, d = 0.f;
            #pragma unroll
            for (int kk = 0; kk < 4; ++kk) {
                float asv = gat_attn[hh * 32 + (tc & 3) * 4 + kk];
                float adv = gat_attn[hh * 32 + 16 + (tc & 3) * 4 + kk];
                s = fmaf(acc[u][kk], asv, s);
                d = fmaf(acc[u][kk], adv, d);
            }
            ps[u] = s; pd[u] = d;
        }
        #pragma unroll
        for (int u = 0; u < 4; ++u) {
            ps[u] += __shfl_xor(ps[u], 1); ps[u] += __shfl_xor(ps[u], 2);
            pd[u] += __shfl_xor(pd[u], 1); pd[u] += __shfl_xor(pd[u], 2);
        }
        if ((tc & 3) == 0) {
            #pragma unroll
            for (int u = 0; u < 4; ++u) {
                int n = n0 + tr * 4 + u;
                if (n < N_CPGS) {
                    ws[W_SSRC + ((size_t)n * 4 + b) * 4 + hh] = ps[u];
                    ws[W_SDST + ((size_t)n * 4 + b) * 4 + hh] = pd[u];
                }
            }
        }
    }
}

// ================= L3: k_sf2 — block 0: scan; blocks 1-80: FFT stage 2 =================
__global__ __launch_bounds__(1024) void k_sf2(float* __restrict__ ws) {
    int t = threadIdx.x;
    if (blockIdx.x == 0) {
        const int* cnt = (const int*)(ws + W_COUNTS);
        int* offs = (int*)(ws + W_OFFS);
        int* cur  = (int*)(ws + W_CURSOR);
        int i0 = t * 20;
        int s = 0;
        for (int i = 0; i < 20; ++i) { int idx = i0 + i; if (idx < N_CPGS) s += cnt[idx]; }
        __shared__ int sd[1024];
        sd[t] = s; __syncthreads();
        for (int off = 1; off < 1024; off <<= 1) {
            int v = (t >= off) ? sd[t - off] : 0;
            __syncthreads();
            sd[t] += v;
            __syncthreads();
        }
        int run = sd[t] - s;
        for (int i = 0; i < 20; ++i) {
            int idx = i0 + i;
            if (idx < N_CPGS) { offs[idx] = run; cur[idx] = run; run += cnt[idx]; }
        }
        if (t == 1023) offs[N_CPGS] = sd[1023];
        return;
    }
    // FFT stage 2: partial over n1-chunk ns of 25
    int bb = blockIdx.x - 1;           // 0..79
    int kb = bb >> 1;
    int ns = (bb & 1) * 4 + (t >> 8);  // 0..7
    int k = kb * 256 + (t & 255);
    int n1b = ns * 25;
    int k2 = k % 100;
    const float4* Yp = (const float4*)(ws + W_Y);
    constexpr float W0 = 6.2831853071795864769f / 20000.f;
    float dc, dsn;
    { float sn, cn; sincosf(W0 * (float)k, &sn, &cn); dc = cn; dsn = -sn; }
    float c, s;
    { int m = (k * n1b) % 20000; float sn, cn; sincosf(W0 * (float)m, &sn, &cn); c = cn; s = -sn; }
    float xr0 = 0.f, xi0 = 0.f, xr1 = 0.f, xi1 = 0.f;
    float xr2 = 0.f, xi2 = 0.f, xr3 = 0.f, xi3 = 0.f;
    #pragma unroll 5
    for (int j = 0; j < 25; ++j) {
        size_t base = ((size_t)(n1b + j) * FN2 + k2) * 2;   // float4 units
        float4 y01 = Yp[base], y23 = Yp[base + 1];
        xr0 = fmaf(y01.x, c, xr0); xr0 = fmaf(-y01.y, s, xr0);
        xi0 = fmaf(y01.x, s, xi0); xi0 = fmaf( y01.y, c, xi0);
        xr1 = fmaf(y01.z, c, xr1); xr1 = fmaf(-y01.w, s, xr1);
        xi1 = fmaf(y01.z, s, xi1); xi1 = fmaf( y01.w, c, xi1);
        xr2 = fmaf(y23.x, c, xr2); xr2 = fmaf(-y23.y, s, xr2);
        xi2 = fmaf(y23.x, s, xi2); xi2 = fmaf( y23.y, c, xi2);
        xr3 = fmaf(y23.z, c, xr3); xr3 = fmaf(-y23.w, s, xr3);
        xi3 = fmaf(y23.z, s, xi3); xi3 = fmaf( y23.w, c, xi3);
        float tc_ = c * dc - s * dsn; s = s * dc + c * dsn; c = tc_;
    }
    float* p = ws + W_P2 + ((size_t)ns * KPAD + k) * 8;
    p[0] = xr0; p[1] = xi0; p[2] = xr1; p[3] = xi1;
    p[4] = xr2; p[5] = xi2; p[6] = xr3; p[7] = xi3;
}

// ================= L4: k_scatmagr =================
__global__ __launch_bounds__(256) void k_scatmagr(const int* __restrict__ ei,
                                                  float* __restrict__ ws) {
    int t = threadIdx.x;
    if (blockIdx.x < HB) {
        int e = blockIdx.x * 256 + t;
        if (e < NEDGE) {
            int s = ei[e], d = ei[NEDGE + e];
            int pos = atomicAdd((int*)(ws + W_CURSOR) + d, 1);
            ((int*)(ws + W_SORTSRC))[pos] = s;
        }
        return;
    }
    int gid = (blockIdx.x - HB) * 256 + t;
    bool ok = gid < BZ * NF;
    int b = ok ? gid / NF : 0;
    int k = ok ? gid - b * NF : 0;
    float m = 0.f;
    if (ok) {
        float re = 0.f, im = 0.f;
        const float* p = ws + W_P2 + (size_t)k * 8 + b * 2;
        #pragma unroll
        for (int ns = 0; ns < NS2; ++ns) { re += p[0]; im += p[1]; p += (size_t)KPAD * 8; }
        m = log1pf(sqrtf(re * re + im * im));
        ws[W_MAG + (size_t)b * NF + k] = m;
    }
    float msq = ok ? m * m : 0.f;
    #pragma unroll
    for (int bb = 0; bb < 4; ++bb) {
        float v = (ok && b == bb) ? msq : 0.f;
        v = wred_sum(v);
        if ((t & 63) == 0) atomicAdd(ws + W_NORMSQ + bb, v);
    }
}

// ================= L5: k_gatdots — [0,GATB): 4-batch GAT; [GATB,GATB+384): dots =========
__global__ __launch_bounds__(256) void k_gatdots(
    const float* __restrict__ fftw1, const float* __restrict__ plW,
    const float* __restrict__ plalpha, const float* __restrict__ fw,
    float* __restrict__ ws)
{
    int t = threadIdx.x;
    if (blockIdx.x < GATB) {
        // ---- GAT: all 4 batches per dst; 4 concurrent gather chains ----
        int w = t >> 6, lane = t & 63;
        int wv = blockIdx.x * 4 + w;                   // 0..4095
        int egrp = lane >> 4, fgrp = lane & 15;
        int hh = fgrp >> 2;
        const int* offs = (const int*)(ws + W_OFFS);
        const int* ssrt = (const int*)(ws + W_SORTSRC);
        const float4* s4src = (const float4*)(ws + W_SSRC);
        const float4* s4dst = (const float4*)(ws + W_SDST);
        const uint2* hbp = (const uint2*)(ws + W_H);   // row (n*4+b): uint2 idx n*64+b*16
        float gacc[4][4] = {};                         // [b][k]

        __shared__ float elds[4][4][4][68];            // [wave][b][head][edge]
        __shared__ int   slds[4][68];
        __shared__ float gred[4][4][64];               // [wave][b][feat]

        for (int dst = wv; dst < N_CPGS; dst += 4 * GATB) {
            int o0 = offs[dst], o1 = offs[dst + 1];
            if (o0 == o1) continue;                    // gelu(0) = 0
            float4 sd4[4];
            #pragma unroll
            for (int b = 0; b < 4; ++b) sd4[b] = s4dst[(size_t)dst * 4 + b];
            float av[4][4] = {};                       // [b][k]
            float es[4] = {};                          // [b] exp-sums (lane's head)
            for (int c0 = o0; c0 < o1; c0 += 64) {
                int cnt = min(64, o1 - c0);
                int s = 0;
                if (lane < cnt) s = ssrt[c0 + lane];
                slds[w][lane] = s;
                #pragma unroll
                for (int b = 0; b < 4; ++b) {
                    float v0 = 0.f, v1 = 0.f, v2 = 0.f, v3 = 0.f;
                    if (lane < cnt) {
                        float4 ss = s4src[(size_t)s * 4 + b];
                        v0 = ss.x + sd4[b].x; v0 = (v0 >= 0.f) ? v0 : 0.2f * v0; v0 = __expf(v0);
                        v1 = ss.y + sd4[b].y; v1 = (v1 >= 0.f) ? v1 : 0.2f * v1; v1 = __expf(v1);
                        v2 = ss.z + sd4[b].z; v2 = (v2 >= 0.f) ? v2 : 0.2f * v2; v2 = __expf(v2);
                        v3 = ss.w + sd4[b].w; v3 = (v3 >= 0.f) ? v3 : 0.2f * v3; v3 = __expf(v3);
                    }
                    elds[w][b][0][lane] = v0; elds[w][b][1][lane] = v1;
                    elds[w][b][2][lane] = v2; elds[w][b][3][lane] = v3;
                }
                // wave-synchronous; 4 edges x 4 batches per iteration
                int niter = (cnt + 3) >> 2;
                for (int i = 0; i < niter; ++i) {
                    int j = (i << 2) + egrp;
                    int sj = slds[w][j];
                    const uint2* hp = hbp + (size_t)sj * 64 + fgrp;
                    float e0 = elds[w][0][hh][j];
                    float e1 = elds[w][1][hh][j];
                    float e2 = elds[w][2][hh][j];
                    float e3 = elds[w][3][hh][j];
                    uint2 h0 = hp[0], h1 = hp[16], h2 = hp[32], h3 = hp[48];
                    es[0] += e0; es[1] += e1; es[2] += e2; es[3] += e3;
                    av[0][0] = fmaf(e0, bf2f((unsigned short)(h0.x & 0xffffu)), av[0][0]);
                    av[0][1] = fmaf(e0, bf2f((unsigned short)(h0.x >> 16)),     av[0][1]);
                    av[0][2] = fmaf(e0, bf2f((unsigned short)(h0.y & 0xffffu)), av[0][2]);
                    av[0][3] = fmaf(e0, bf2f((unsigned short)(h0.y >> 16)),     av[0][3]);
                    av[1][0] = fmaf(e1, bf2f((unsigned short)(h1.x & 0xffffu)), av[1][0]);
                    av[1][1] = fmaf(e1, bf2f((unsigned short)(h1.x >> 16)),     av[1][1]);
                    av[1][2] = fmaf(e1, bf2f((unsigned short)(h1.y & 0xffffu)), av[1][2]);
                    av[1][3] = fmaf(e1, bf2f((unsigned short)(h1.y >> 16)),     av[1][3]);
                    av[2][0] = fmaf(e2, bf2f((unsigned short)(h2.x & 0xffffu)), av[2][0]);
                    av[2][1] = fmaf(e2, bf2f((unsigned short)(h2.x >> 16)),     av[2][1]);
                    av[2][2] = fmaf(e2, bf2f((unsigned short)(h2.y & 0xffffu)), av[2][2]);
                    av[2][3] = fmaf(e2, bf2f((unsigned short)(h2.y >> 16)),     av[2][3]);
                    av[3][0] = fmaf(e3, bf2f((unsigned short)(h3.x & 0xffffu)), av[3][0]);
                    av[3][1] = fmaf(e3, bf2f((unsigned short)(h3.x >> 16)),     av[3][1]);
                    av[3][2] = fmaf(e3, bf2f((unsigned short)(h3.y & 0xffffu)), av[3][2]);
                    av[3][3] = fmaf(e3, bf2f((unsigned short)(h3.y >> 16)),     av[3][3]);
                }
            }
            // combine egrp subgroups (lane bits 4,5); es -> full softmax denominator
            #pragma unroll
            for (int b = 0; b < 4; ++b) {
                float sden = es[b];
                sden += __shfl_xor(sden, 16); sden += __shfl_xor(sden, 32);
                float inv = 1.f / (sden + 1e-8f);
                #pragma unroll
                for (int k = 0; k < 4; ++k) {
                    float a = av[b][k];
                    a += __shfl_xor(a, 16); a += __shfl_xor(a, 32);
                    gacc[b][k] += gelu_f(a * inv);
                }
            }
        }
        if (egrp == 0) {
            #pragma unroll
            for (int b = 0; b < 4; ++b)
                #pragma unroll
                for (int k = 0; k < 4; ++k)
                    gred[w][b][fgrp * 4 + k] = gacc[b][k];
        }
        __syncthreads();
        {
            int b = t >> 6, f = t & 63;
            atomicAdd(ws + W_GATMEAN + b * 64 + f,
                      gred[0][b][f] + gred[1][b][f] + gred[2][b][f] + gred[3][b][f]);
        }
        return;
    }
    // ---- dots ----
    int bb2 = blockIdx.x - GATB;
    int m = bb2 >> 7;
    int r = bb2 & 127;
    const float* mag = ws + W_MAG;
    float smx = ws[W_SMSTAT], ssm = ws[W_SMSTAT + 1];
    float sc_fw = (float)NF / ssm;
    float inv_n0 = 1.f / (sqrtf(ws[W_NORMSQ + 0]) + 1e-8f);
    float inv_n1 = 1.f / (sqrtf(ws[W_NORMSQ + 1]) + 1e-8f);
    float inv_n2 = 1.f / (sqrtf(ws[W_NORMSQ + 2]) + 1e-8f);
    float inv_n3 = 1.f / (sqrtf(ws[W_NORMSQ + 3]) + 1e-8f);
    const float* row = ((m == 0) ? fftw1 : (m == 1) ? plW : plalpha) + (size_t)r * NF;
    float a0 = 0.f, a1 = 0.f, a2 = 0.f, a3 = 0.f;
    for (int k = t; k < NF; k += 256) {
        float wv = row[k];
        float g0 = mag[k], g1 = mag[NF + k], g2 = mag[2 * NF + k], g3 = mag[3 * NF + k];
        if (m == 0) {
            float s = expf(fw[k] - smx) * sc_fw;
            wv *= s;
            a0 = fmaf(wv, g0, a0); a1 = fmaf(wv, g1, a1); a2 = fmaf(wv, g2, a2); a3 = fmaf(wv, g3, a3);
        } else if (m == 1) {
            a0 = fmaf(wv, g0, a0); a1 = fmaf(wv, g1, a1); a2 = fmaf(wv, g2, a2); a3 = fmaf(wv, g3, a3);
        } else {
            wv = 1.f / (1.f + expf(-wv));   // sigmoid(pl_alpha)
            a0 = fmaf(wv, g0 * g0 * inv_n0, a0); a1 = fmaf(wv, g1 * g1 * inv_n1, a1);
            a2 = fmaf(wv, g2 * g2 * inv_n2, a2); a3 = fmaf(wv, g3 * g3 * inv_n3, a3);
        }
    }
    __shared__ float sd[256];
    float acc[4] = {a0, a1, a2, a3};
    #pragma unroll
    for (int bb = 0; bb < 4; ++bb) {
        sd[t] = acc[bb]; __syncthreads();
        for (int o = 128; o; o >>= 1) { if (t < o) sd[t] += sd[t + o]; __syncthreads(); }
        if (t == 0) ws[W_D + ((size_t)m * 128 + r) * 4 + bb] = sd[0];
        __syncthreads();
    }
}

// ================= L6: k_final =================
DEVFN float ln64(float v, const float* g, const float* bt, int lane) {
    float mn = wred_sum(v) * (1.f / 64.f);
    float d = v - mn;
    float var = wred_sum(d * d) * (1.f / 64.f);
    return d * (1.0f / sqrtf(var + 1e-5f)) * g[lane] + bt[lane];
}
DEVFN void ln128(float& v0, float& v1, const float* g, const float* bt, int lane) {
    float mn = wred_sum(v0 + v1) * (1.f / 128.f);
    float d0 = v0 - mn, d1 = v1 - mn;
    float var = wred_sum(d0 * d0 + d1 * d1) * (1.f / 128.f);
    float rs = 1.0f / sqrtf(var + 1e-5f);
    v0 = d0 * rs * g[lane] + bt[lane];
    v1 = d1 * rs * g[lane + 64] + bt[lane + 64];
}
DEVFN float dotW128(const float* __restrict__ W, const float* __restrict__ v, int c) {
    const float4* w4 = (const float4*)(W + (size_t)c * 128);
    float acc = 0.f;
    #pragma unroll
    for (int q = 0; q < 32; ++q) {
        float4 wv = w4[q];
        const float* vv = v + q * 4;
        acc = fmaf(wv.x, vv[0], acc); acc = fmaf(wv.y, vv[1], acc);
        acc = fmaf(wv.z, vv[2], acc); acc = fmaf(wv.w, vv[3], acc);
    }
    return acc;
}
DEVFN float dotW64(const float* __restrict__ W, const float* __restrict__ v, int c) {
    const float4* w4 = (const float4*)(W + (size_t)c * 64);
    float acc = 0.f;
    #pragma unroll
    for (int q = 0; q < 16; ++q) {
        float4 wv = w4[q];
        const float* vv = v + q * 4;
        acc = fmaf(wv.x, vv[0], acc); acc = fmaf(wv.y, vv[1], acc);
        acc = fmaf(wv.z, vv[2], acc); acc = fmaf(wv.w, vv[3], acc);
    }
    return acc;
}

__global__ __launch_bounds__(256) void k_final(
    const float* __restrict__ fft_b1, const float* __restrict__ fft_ln1_g, const float* __restrict__ fft_ln1_b,
    const float* __restrict__ fft_w2, const float* __restrict__ fft_b2,
    const float* __restrict__ fft_ln2_g, const float* __restrict__ fft_ln2_b,
    const float* __restrict__ gp_w, const float* __restrict__ gp_b,
    const float* __restrict__ gp_ln_g, const float* __restrict__ gp_ln_b,
    const float* __restrict__ pl_eta, const float* __restrict__ pl_bias,
    const float* __restrict__ pn_g, const float* __restrict__ pn_b,
    const float* __restrict__ pp_w, const float* __restrict__ pp_b,
    const float* __restrict__ pp_ln_g, const float* __restrict__ pp_ln_b,
    const float* __restrict__ gate_w1, const float* __restrict__ gate_b1,
    const float* __restrict__ gate_w2, const float* __restrict__ gate_b2,
    const float* __restrict__ head_w1, const float* __restrict__ head_b1,
    const float* __restrict__ head_w2, const float* __restrict__ head_b2,
    float* __restrict__ ws, float* __restrict__ out)
{
    int t = threadIdx.x, b = t >> 6, lane = t & 63;
    __shared__ float vlds[4][256];
    float* vb = vlds[b];
    const float* D = ws + W_D;
    int r0 = lane, r1 = lane + 64;

    float f0 = D[(0 * 128 + r0) * 4 + b] + fft_b1[r0];
    float f1 = D[(0 * 128 + r1) * 4 + b] + fft_b1[r1];
    ln128(f0, f1, fft_ln1_g, fft_ln1_b, lane);
    vb[lane] = gelu_f(f0); vb[64 + lane] = gelu_f(f1);
    float catf = ln64(dotW128(fft_w2, vb, lane) + fft_b2[lane], fft_ln2_g, fft_ln2_b, lane);

    float hgm = (ws[W_H0SUM + b * 64 + lane] + ws[W_GATMEAN + b * 64 + lane]) * (1.f / N_CPGS);
    vb[lane] = hgm;
    float catg = ln64(dotW64(gp_w, vb, lane) + gp_b[lane], gp_ln_g, gp_ln_b, lane);

    float eta = pl_eta[0];
    float ys0 = D[(1 * 128 + r0) * 4 + b] + pl_bias[r0];
    float ys1 = D[(1 * 128 + r1) * 4 + b] + pl_bias[r1];
    float q0 = D[(2 * 128 + r0) * 4 + b];
    float q1 = D[(2 * 128 + r1) * 4 + b];
    float u0 = gelu_f(ys0 + eta * tanhf(ys0) * q0);
    float u1 = gelu_f(ys1 + eta * tanhf(ys1) * q1);
    ln128(u0, u1, pn_g, pn_b, lane);
    vb[lane] = u0; vb[64 + lane] = u1;
    float catp = ln64(dotW128(pp_w, vb, lane) + pp_b[lane], pp_ln_g, pp_ln_b, lane);

    vb[lane] = catf; vb[64 + lane] = catg; vb[128 + lane] = catp;
    if (lane < 6) {
        float a = gate_b1[lane];
        const float* wrow = gate_w1 + lane * 192;
        #pragma unroll 4
        for (int j = 0; j < 192; ++j) a = fmaf(wrow[j], vb[j], a);
        vb[192 + lane] = gelu_f(a);
    }
    float gv[3];
    #pragma unroll
    for (int c = 0; c < 3; ++c) {
        float a = gate_b2[c];
        #pragma unroll
        for (int j = 0; j < 6; ++j) a = fmaf(gate_w2[c * 6 + j], vb[192 + j], a);
        gv[c] = a;
    }
    float gmx = fmaxf(gv[0], fmaxf(gv[1], gv[2]));
    float e0 = expf(gv[0] - gmx), e1 = expf(gv[1] - gmx), e2 = expf(gv[2] - gmx);
    float inv = 1.f / (e0 + e1 + e2);
    float fus = catf * (e0 * inv) + catg * (e1 * inv) + catp * (e2 * inv);

    vb[lane] = fus;
    float hval = 0.f;
    if (lane < 32) {
        float a = dotW64(head_w1, vb, lane) + head_b1[lane];
        hval = gelu_f(a) * head_w2[lane];
    }
    float o = wred_sum(hval);
    if (lane == 0) out[b] = o + head_b2[0];
}

// ---------------- launch ----------------
extern "C" void kernel_launch(void* const* d_in, const int* in_sizes, int n_in,
                              void* d_out, int out_size, void* d_ws, size_t ws_size,
                              hipStream_t stream) {
    (void)in_sizes; (void)n_in; (void)out_size; (void)ws_size;
    const float* x        = (const float*)d_in[0];
    const int*   ei       = (const int*)d_in[1];
    const float* fw       = (const float*)d_in[2];
    const float* fft_w1   = (const float*)d_in[3];
    const float* fft_b1   = (const float*)d_in[4];
    const float* fft_ln1g = (const float*)d_in[5];
    const float* fft_ln1b = (const float*)d_in[6];
    const float* fft_w2   = (const float*)d_in[7];
    const float* fft_b2   = (const float*)d_in[8];
    const float* fft_ln2g = (const float*)d_in[9];
    const float* fft_ln2b = (const float*)d_in[10];
    const float* ge_w     = (const float*)d_in[11];
    const float* ge_b     = (const float*)d_in[12];
    const float* ge_g     = (const float*)d_in[13];
    const float* ge_beta  = (const float*)d_in[14];
    const float* gat_w    = (const float*)d_in[15];
    const float* gat_attn = (const float*)d_in[16];
    const float* gp_w     = (const float*)d_in[17];
    const float* gp_b     = (const float*)d_in[18];
    const float* gp_ln_g  = (const float*)d_in[19];
    const float* gp_ln_b  = (const float*)d_in[20];
    const float* pl_W     = (const float*)d_in[21];
    const float* pl_alpha = (const float*)d_in[22];
    const float* pl_eta   = (const float*)d_in[23];
    const float* pl_bias  = (const float*)d_in[24];
    const float* pn_g     = (const float*)d_in[25];
    const float* pn_b     = (const float*)d_in[26];
    const float* pp_w     = (const float*)d_in[27];
    const float* pp_b     = (const float*)d_in[28];
    const float* pp_ln_g  = (const float*)d_in[29];
    const float* pp_ln_b  = (const float*)d_in[30];
    const float* gate_w1  = (const float*)d_in[31];
    const float* gate_b1  = (const float*)d_in[32];
    const float* gate_w2  = (const float*)d_in[33];
    const float* gate_b2  = (const float*)d_in[34];
    const float* head_w1  = (const float*)d_in[35];
    const float* head_b1  = (const float*)d_in[36];
    const float* head_w2  = (const float*)d_in[37];
    const float* head_b2  = (const float*)d_in[38];

    float* ws  = (float*)d_ws;
    float* out = (float*)d_out;

    k_pre<<<26, 256, 0, stream>>>(x, ge_w, ge_b, fw, ws);
    k_node<<<4 * TILES + HB + 400, 256, 0, stream>>>(x, ge_w, ge_b, ge_g, ge_beta,
                                                     gat_w, gat_attn, ei, ws);
    k_sf2<<<81, 1024, 0, stream>>>(ws);
    k_scatmagr<<<HB + (BZ * NF + 255) / 256, 256, 0, stream>>>(ei, ws);
    k_gatdots<<<GATB + 384, 256, 0, stream>>>(fft_w1, pl_W, pl_alpha, fw, ws);
    k_final<<<1, 256, 0, stream>>>(fft_b1, fft_ln1g, fft_ln1b, fft_w2, fft_b2, fft_ln2g, fft_ln2b,
                                   gp_w, gp_b, gp_ln_g, gp_ln_b, pl_eta, pl_bias, pn_g, pn_b,
                                   pp_w, pp_b, pp_ln_g, pp_ln_b, gate_w1, gate_b1, gate_w2, gate_b2,
                                   head_w1, head_b1, head_w2, head_b2, ws, out);
}

// Round 7
// 213.967 us; speedup vs baseline: 1.0566x; 1.0566x over previous
//
#include <hip/hip_runtime.h>
#include <math.h>

// ---------------- problem constants ----------------
constexpr int N_CPGS = 20000;
constexpr int NF     = 10001;      // N/2+1
constexpr int BZ     = 4;
constexpr int NEDGE  = 320000;
constexpr int KPAD   = 10240;      // padded freq count (40 blocks * 256)
// FFT decomposition: n = n1 + 200*n2, n1 in [0,200), n2 in [0,100)
constexpr int FN1    = 200;
constexpr int FN2    = 100;
constexpr int NS2    = 8;          // stage-2 n1-chunks (25 each)
constexpr int TILES  = (N_CPGS + 63) / 64;   // 313
constexpr int HB     = NEDGE / 256;          // 1250 hist/scatter blocks
constexpr int DOTSB  = 384;                  // dots blocks (placed FIRST in k_gatdots)

// ---------------- workspace layout (float offsets) ----------------
constexpr size_t W_XMEAN   = 0;        // 4
constexpr size_t W_SMSTAT  = 64;       // 2
constexpr size_t W_NORMSQ  = 128;      // 4   [zeroed in k_pre]
constexpr size_t W_H0SUM   = 192;      // 256 [zeroed in k_pre]
constexpr size_t W_GATMEAN = 448;      // 256 [zeroed in k_pre]
constexpr size_t W_PREP    = 704;      // 8 (mw, mb, A, C, D)
constexpr size_t W_D       = 768;      // 3*128*4
constexpr size_t W_MAG     = 2304;     // BZ*NF = 40004
constexpr size_t W_SSRC    = 42368;    // float[(b*N+n)*4+h] = 320000  (per-batch layout!)
constexpr size_t W_SDST    = 362368;   // 320000
constexpr size_t W_H       = 682368;   // bf16[(b*N+n)*64+f] = 5.12MB  (per-batch layout!)
constexpr size_t W_Y       = 5802368;  // float2[(n1*100+k2)*4+b] = 160000 floats
constexpr size_t W_P2      = 5962368;  // NS2*KPAD*8 = 655360 floats
constexpr size_t W_COUNTS  = 9079168;  // int 20000 [zeroed in k_pre]
constexpr size_t W_OFFS    = 9099168;  // int 20001
constexpr size_t W_CURSOR  = 9119232;  // int 20000
constexpr size_t W_SORTSRC = 9139232;  // int 320000
// end: 9459232 floats = 37,836,928 bytes

#define DEVFN static __device__ __forceinline__

// Fast gelu: A&S 7.1.26 erf, |abs err| <= 1.5e-7.
DEVFN float gelu_f(float v) {
    float ax = fabsf(v) * 0.70710678118654752440f;
    float t = 1.0f / fmaf(0.3275911f, ax, 1.0f);
    float p = fmaf(t, 1.061405429f, -1.453152027f);
    p = fmaf(p, t, 1.421413741f);
    p = fmaf(p, t, -0.284496736f);
    p = fmaf(p, t, 0.254829592f);
    p = p * t;
    float e = __expf(-ax * ax);
    float er = copysignf(fmaf(-p, e, 1.0f), v);
    return 0.5f * v * (1.0f + er);
}

DEVFN float wred_sum(float v) {
    #pragma unroll
    for (int m = 32; m; m >>= 1) v += __shfl_xor(v, m);
    return v;
}

DEVFN unsigned int bfr(float f) {            // fp32 -> bf16 bits, RNE
    unsigned int u = __float_as_uint(f);
    return (u + 0x7fffu + ((u >> 16) & 1u)) >> 16;
}
DEVFN float bf2f(unsigned short v) { return __uint_as_float(((unsigned int)v) << 16); }

// ================= L1: k_pre =================
__global__ void k_pre(const float* __restrict__ x, const float* __restrict__ ge_w,
                      const float* __restrict__ ge_b, const float* __restrict__ fw,
                      float* __restrict__ ws) {
    int bb = blockIdx.x, t = threadIdx.x;
    __shared__ float sd[256];
    if (bb < 4) {
        const float4* x4 = (const float4*)(x + (size_t)bb * N_CPGS);
        float s = 0.f;
        for (int i = t; i < N_CPGS / 4; i += 256) {
            float4 v = x4[i];
            s += (v.x + v.y) + (v.z + v.w);
        }
        sd[t] = s; __syncthreads();
        for (int o = 128; o; o >>= 1) { if (t < o) sd[t] += sd[t + o]; __syncthreads(); }
        if (t == 0) ws[W_XMEAN + bb] = sd[0] * (1.0f / N_CPGS);
    } else if (bb == 4) {
        for (int i = t; i < (int)(W_PREP - W_NORMSQ); i += 256) ws[W_NORMSQ + i] = 0.f;
        if (t < 64) {
            float w = ge_w[t], b = ge_b[t];
            float mw = wred_sum(w) * (1.f / 64.f);
            float mb = wred_sum(b) * (1.f / 64.f);
            float wc = w - mw, bc = b - mb;
            float A = wred_sum(wc * wc) * (1.f / 64.f);
            float C = wred_sum(wc * bc) * (1.f / 64.f);
            float D = wred_sum(bc * bc) * (1.f / 64.f);
            if (t == 0) { float* p = ws + W_PREP; p[0] = mw; p[1] = mb; p[2] = A; p[3] = C; p[4] = D; }
        }
    } else if (bb == 5) {
        float mx = -1e30f;
        for (int i = t; i < NF; i += 256) mx = fmaxf(mx, fw[i]);
        sd[t] = mx; __syncthreads();
        for (int o = 128; o; o >>= 1) { if (t < o) sd[t] = fmaxf(sd[t], sd[t + o]); __syncthreads(); }
        mx = sd[0]; __syncthreads();
        float s = 0.f;
        for (int i = t; i < NF; i += 256) s += expf(fw[i] - mx);
        sd[t] = s; __syncthreads();
        for (int o = 128; o; o >>= 1) { if (t < o) sd[t] += sd[t + o]; __syncthreads(); }
        if (t == 0) { ws[W_SMSTAT] = mx; ws[W_SMSTAT + 1] = sd[0]; }
    } else {
        int base = (bb - 6) * 1000;
        int* cnt = (int*)(ws + W_COUNTS);
        for (int i = t; i < 1000; i += 256) cnt[base + i] = 0;
    }
}

// ================= L2: k_node — node tiles + edge histogram + FFT stage 1 =================
__global__ __launch_bounds__(256) void k_node(
    const float* __restrict__ x, const float* __restrict__ ge_w, const float* __restrict__ ge_b,
    const float* __restrict__ ge_g, const float* __restrict__ ge_beta,
    const float* __restrict__ gat_w, const float* __restrict__ gat_attn,
    const int* __restrict__ ei, float* __restrict__ ws)
{
    int t = threadIdx.x;
    int nb = blockIdx.x;
    if (nb >= 4 * TILES) {
        int r = nb - 4 * TILES;
        if (r < HB) {                                  // fused edge histogram
            int e = r * 256 + t;
            if (e < NEDGE) atomicAdd((int*)(ws + W_COUNTS) + ei[NEDGE + e], 1);
        } else {                                       // FFT stage 1
            int fb = r - HB;                           // 0..399
            int b = fb / 100;
            int n1base = (fb % 100) * 2;
            int n1l = t >> 7, k2 = t & 127;
            __shared__ float xs[2][100];
            float xm = ws[W_XMEAN + b];
            for (int i = t; i < 200; i += 256) {
                int nl = (i >= 100) ? 1 : 0, n2 = (i >= 100) ? i - 100 : i;
                xs[nl][n2] = x[(size_t)b * N_CPGS + n1base + nl + 200 * n2] - xm;
            }
            __syncthreads();
            int k2e = (k2 < 100) ? k2 : 0;
            constexpr float T100 = 6.2831853071795864769f / 100.f;
            float dc, dsn;
            { float sn, cn; sincosf(T100 * (float)k2e, &sn, &cn); dc = cn; dsn = -sn; }
            float yr = 0.f, yi = 0.f;
            #pragma unroll
            for (int half = 0; half < 2; ++half) {
                float c, s;
                { int m = (k2e * (half * 50)) % 100; float sn, cn; sincosf(T100 * (float)m, &sn, &cn); c = cn; s = -sn; }
                #pragma unroll 5
                for (int j = 0; j < 50; ++j) {
                    float xv = xs[n1l][half * 50 + j];
                    yr = fmaf(xv, c, yr); yi = fmaf(xv, s, yi);
                    float tc_ = c * dc - s * dsn; s = s * dc + c * dsn; c = tc_;
                }
            }
            if (k2 < 100)
                ((float2*)(ws + W_Y))[((size_t)(n1base + n1l) * FN2 + k2) * 4 + b] = make_float2(yr, yi);
        }
        return;
    }
    int b = nb / TILES;
    int tile = nb % TILES;
    int n0 = tile * 64;

    __shared__ __align__(16) float h0T[64 * 68];   // [feat j][node]
    __shared__ __align__(16) float gwT[64 * 68];   // [j][i] = gat_w[i][j]
    __shared__ float xsv[64], rss[64];

    const float* prep = ws + W_PREP;
    float mw = prep[0], mb = prep[1], A = prep[2], C = prep[3], Dd = prep[4];

    for (int idx = t; idx < 4096; idx += 256) { int i = idx >> 6, j = idx & 63; gwT[j * 68 + i] = gat_w[idx]; }
    if (t < 64) {
        int n = n0 + t;
        float xv = (n < N_CPGS) ? x[(size_t)b * N_CPGS + n] : 0.f;
        xsv[t] = xv;
        float var = xv * xv * A + 2.f * xv * C + Dd;
        rss[t] = 1.0f / sqrtf(var + 1e-5f);
    }
    __syncthreads();

    for (int idx = t; idx < 4096; idx += 256) {
        int j = idx >> 6, nd = idx & 63;
        float h0 = 0.f;
        if (n0 + nd < N_CPGS) {
            float v = (xsv[nd] * (ge_w[j] - mw) + (ge_b[j] - mb)) * rss[nd];
            h0 = gelu_f(v * ge_g[j] + ge_beta[j]);
        }
        h0T[j * 68 + nd] = h0;
    }
    __syncthreads();

    // 64x64 @ 64x64 matmul, 16x16 threads, 4x4 micro-tile
    int tr = t >> 4, tc = t & 15;
    float acc[4][4] = {};
    #pragma unroll 8
    for (int j = 0; j < 64; ++j) {
        const float4 av = *(const float4*)&h0T[j * 68 + (tr << 2)];
        const float4 bv = *(const float4*)&gwT[j * 68 + (tc << 2)];
        #pragma unroll
        for (int u = 0; u < 4; ++u) {
            float a = (u == 0) ? av.x : (u == 1) ? av.y : (u == 2) ? av.z : av.w;
            acc[u][0] = fmaf(a, bv.x, acc[u][0]);
            acc[u][1] = fmaf(a, bv.y, acc[u][1]);
            acc[u][2] = fmaf(a, bv.z, acc[u][2]);
            acc[u][3] = fmaf(a, bv.w, acc[u][3]);
        }
    }
    // h0 feature sums
    if (t < 64) {
        float s = 0.f;
        #pragma unroll 8
        for (int nd = 0; nd < 64; ++nd) s += h0T[t * 68 + nd];
        atomicAdd(ws + W_H0SUM + b * 64 + t, s);
    }
    // h write (bf16, per-batch layout [b][n][f] -> XCD-local in k_gat)
    unsigned short* hbp = (unsigned short*)(ws + W_H);
    #pragma unroll
    for (int u = 0; u < 4; ++u) {
        int n = n0 + tr * 4 + u;
        if (n < N_CPGS) {
            unsigned int lo = bfr(acc[u][0]) | (bfr(acc[u][1]) << 16);
            unsigned int hi = bfr(acc[u][2]) | (bfr(acc[u][3]) << 16);
            *(uint2*)(hbp + ((size_t)b * N_CPGS + n) * 64 + tc * 4) = make_uint2(lo, hi);
        }
    }
    // attention scores straight from registers:
    // thread owns h[n=tr*4+u][i=tc*4+kk], head hh=tc>>2, d=(tc&3)*4+kk
    {
        int hh = tc >> 2;
        float ps[4], pd[4];
        #pragma unroll
        for (int u = 0; u < 4; ++u) {
            float s = 0.f, d = 0.f;
            #pragma unroll
            for (int kk = 0; kk < 4; ++kk) {
                float asv = gat_attn[hh * 32 + (tc & 3) * 4 + kk];
                float adv = gat_attn[hh * 32 + 16 + (tc & 3) * 4 + kk];
                s = fmaf(acc[u][kk], asv, s);
                d = fmaf(acc[u][kk], adv, d);
            }
            ps[u] = s; pd[u] = d;
        }
        #pragma unroll
        for (int u = 0; u < 4; ++u) {
            ps[u] += __shfl_xor(ps[u], 1); ps[u] += __shfl_xor(ps[u], 2);
            pd[u] += __shfl_xor(pd[u], 1); pd[u] += __shfl_xor(pd[u], 2);
        }
        if ((tc & 3) == 0) {
            #pragma unroll
            for (int u = 0; u < 4; ++u) {
                int n = n0 + tr * 4 + u;
                if (n < N_CPGS) {
                    ws[W_SSRC + ((size_t)b * N_CPGS + n) * 4 + hh] = ps[u];
                    ws[W_SDST + ((size_t)b * N_CPGS + n) * 4 + hh] = pd[u];
                }
            }
        }
    }
}

// ================= L3: k_sf2 — block 0: scan; blocks 1-80: FFT stage 2 =================
__global__ __launch_bounds__(1024) void k_sf2(float* __restrict__ ws) {
    int t = threadIdx.x;
    if (blockIdx.x == 0) {
        const int* cnt = (const int*)(ws + W_COUNTS);
        int* offs = (int*)(ws + W_OFFS);
        int* cur  = (int*)(ws + W_CURSOR);
        int i0 = t * 20;
        int s = 0;
        for (int i = 0; i < 20; ++i) { int idx = i0 + i; if (idx < N_CPGS) s += cnt[idx]; }
        __shared__ int sd[1024];
        sd[t] = s; __syncthreads();
        for (int off = 1; off < 1024; off <<= 1) {
            int v = (t >= off) ? sd[t - off] : 0;
            __syncthreads();
            sd[t] += v;
            __syncthreads();
        }
        int run = sd[t] - s;
        for (int i = 0; i < 20; ++i) {
            int idx = i0 + i;
            if (idx < N_CPGS) { offs[idx] = run; cur[idx] = run; run += cnt[idx]; }
        }
        if (t == 1023) offs[N_CPGS] = sd[1023];
        return;
    }
    // FFT stage 2: partial over n1-chunk ns of 25
    int bb = blockIdx.x - 1;           // 0..79
    int kb = bb >> 1;
    int ns = (bb & 1) * 4 + (t >> 8);  // 0..7
    int k = kb * 256 + (t & 255);
    int n1b = ns * 25;
    int k2 = k % 100;
    const float4* Yp = (const float4*)(ws + W_Y);
    constexpr float W0 = 6.2831853071795864769f / 20000.f;
    float dc, dsn;
    { float sn, cn; sincosf(W0 * (float)k, &sn, &cn); dc = cn; dsn = -sn; }
    float c, s;
    { int m = (k * n1b) % 20000; float sn, cn; sincosf(W0 * (float)m, &sn, &cn); c = cn; s = -sn; }
    float xr0 = 0.f, xi0 = 0.f, xr1 = 0.f, xi1 = 0.f;
    float xr2 = 0.f, xi2 = 0.f, xr3 = 0.f, xi3 = 0.f;
    #pragma unroll 5
    for (int j = 0; j < 25; ++j) {
        size_t base = ((size_t)(n1b + j) * FN2 + k2) * 2;   // float4 units
        float4 y01 = Yp[base], y23 = Yp[base + 1];
        xr0 = fmaf(y01.x, c, xr0); xr0 = fmaf(-y01.y, s, xr0);
        xi0 = fmaf(y01.x, s, xi0); xi0 = fmaf( y01.y, c, xi0);
        xr1 = fmaf(y01.z, c, xr1); xr1 = fmaf(-y01.w, s, xr1);
        xi1 = fmaf(y01.z, s, xi1); xi1 = fmaf( y01.w, c, xi1);
        xr2 = fmaf(y23.x, c, xr2); xr2 = fmaf(-y23.y, s, xr2);
        xi2 = fmaf(y23.x, s, xi2); xi2 = fmaf( y23.y, c, xi2);
        xr3 = fmaf(y23.z, c, xr3); xr3 = fmaf(-y23.w, s, xr3);
        xi3 = fmaf(y23.z, s, xi3); xi3 = fmaf( y23.w, c, xi3);
        float tc_ = c * dc - s * dsn; s = s * dc + c * dsn; c = tc_;
    }
    float* p = ws + W_P2 + ((size_t)ns * KPAD + k) * 8;
    p[0] = xr0; p[1] = xi0; p[2] = xr1; p[3] = xi1;
    p[4] = xr2; p[5] = xi2; p[6] = xr3; p[7] = xi3;
}

// ================= L4: k_scatmagr =================
__global__ __launch_bounds__(256) void k_scatmagr(const int* __restrict__ ei,
                                                  float* __restrict__ ws) {
    int t = threadIdx.x;
    if (blockIdx.x < HB) {
        int e = blockIdx.x * 256 + t;
        if (e < NEDGE) {
            int s = ei[e], d = ei[NEDGE + e];
            int pos = atomicAdd((int*)(ws + W_CURSOR) + d, 1);
            ((int*)(ws + W_SORTSRC))[pos] = s;
        }
        return;
    }
    int gid = (blockIdx.x - HB) * 256 + t;
    bool ok = gid < BZ * NF;
    int b = ok ? gid / NF : 0;
    int k = ok ? gid - b * NF : 0;
    float m = 0.f;
    if (ok) {
        float re = 0.f, im = 0.f;
        const float* p = ws + W_P2 + (size_t)k * 8 + b * 2;
        #pragma unroll
        for (int ns = 0; ns < NS2; ++ns) { re += p[0]; im += p[1]; p += (size_t)KPAD * 8; }
        m = log1pf(sqrtf(re * re + im * im));
        ws[W_MAG + (size_t)b * NF + k] = m;
    }
    float msq = ok ? m * m : 0.f;
    #pragma unroll
    for (int bb = 0; bb < 4; ++bb) {
        float v = (ok && b == bb) ? msq : 0.f;
        v = wred_sum(v);
        if ((t & 63) == 0) atomicAdd(ws + W_NORMSQ + bb, v);
    }
}

// ======== L5: k_gatdots — blocks [0,DOTSB): dots (drain early); [DOTSB,DOTSB+2048): GAT ====
__global__ __launch_bounds__(256) void k_gatdots(
    const float* __restrict__ fftw1, const float* __restrict__ plW,
    const float* __restrict__ plalpha, const float* __restrict__ fw,
    float* __restrict__ ws)
{
    int t = threadIdx.x;
    if (blockIdx.x >= DOTSB) {
        // ---- GAT: per-batch blocks, XCD swizzle, single-pass softmax, uint2 bf16 gather ----
        int g = blockIdx.x - DOTSB;                    // 0..2047
        int xcd = g & 7;
        int b = xcd >> 1;                              // batch pinned to 2 XCDs
        int blk = ((g >> 3) << 1) | (xcd & 1);         // 0..511
        int w = t >> 6, lane = t & 63;
        int wv = blk * 4 + w;                          // 0..2047
        int egrp = lane >> 4, fgrp = lane & 15;
        int hh = fgrp >> 2;
        const int* offs = (const int*)(ws + W_OFFS);
        const int* ssrt = (const int*)(ws + W_SORTSRC);
        const float4* s4src = (const float4*)(ws + W_SSRC);
        const float4* s4dst = (const float4*)(ws + W_SDST);
        const uint2* hbp = (const uint2*)(ws + W_H);   // row (b*N+n): uint2 idx (b*N+n)*16
        size_t bN = (size_t)b * N_CPGS;
        float gacc0 = 0.f, gacc1 = 0.f, gacc2 = 0.f, gacc3 = 0.f;

        __shared__ float elds[4][4][68];               // [wave][head][edge]
        __shared__ int   slds[4][68];
        __shared__ float gred[4][64];

        for (int dst = wv; dst < N_CPGS; dst += 2048) {
            int o0 = offs[dst], o1 = offs[dst + 1];
            if (o0 == o1) continue;                    // gelu(0) = 0
            float4 sd4 = s4dst[bN + dst];
            float es = 0.f;                            // exp-sum for lane's head (partial over egrp)
            float a0 = 0.f, a1 = 0.f, a2 = 0.f, a3 = 0.f;
            for (int c0 = o0; c0 < o1; c0 += 64) {
                int cnt = min(64, o1 - c0);
                float v0 = 0.f, v1 = 0.f, v2 = 0.f, v3 = 0.f;
                int s = 0;
                if (lane < cnt) {
                    s = ssrt[c0 + lane];
                    float4 ss = s4src[bN + s];
                    v0 = ss.x + sd4.x; v0 = (v0 >= 0.f) ? v0 : 0.2f * v0; v0 = __expf(v0);
                    v1 = ss.y + sd4.y; v1 = (v1 >= 0.f) ? v1 : 0.2f * v1; v1 = __expf(v1);
                    v2 = ss.z + sd4.z; v2 = (v2 >= 0.f) ? v2 : 0.2f * v2; v2 = __expf(v2);
                    v3 = ss.w + sd4.w; v3 = (v3 >= 0.f) ? v3 : 0.2f * v3; v3 = __expf(v3);
                }
                slds[w][lane] = s;                     // zero-padded tail
                elds[w][0][lane] = v0; elds[w][1][lane] = v1;
                elds[w][2][lane] = v2; elds[w][3][lane] = v3;
                // wave-synchronous; 4 edges per iteration, exp-sum fused into gather loop
                int niter = (cnt + 3) >> 2;
                for (int i = 0; i < niter; ++i) {
                    int j = (i << 2) + egrp;
                    float e = elds[w][hh][j];
                    int sj = slds[w][j];
                    uint2 hv = hbp[(bN + sj) * 16 + fgrp];
                    es += e;
                    a0 = fmaf(e, bf2f((unsigned short)(hv.x & 0xffffu)), a0);
                    a1 = fmaf(e, bf2f((unsigned short)(hv.x >> 16)),     a1);
                    a2 = fmaf(e, bf2f((unsigned short)(hv.y & 0xffffu)), a2);
                    a3 = fmaf(e, bf2f((unsigned short)(hv.y >> 16)),     a3);
                }
            }
            // combine the 4 egrp subgroups (lane bits 4,5)
            es += __shfl_xor(es, 16); es += __shfl_xor(es, 32);
            a0 += __shfl_xor(a0, 16); a0 += __shfl_xor(a0, 32);
            a1 += __shfl_xor(a1, 16); a1 += __shfl_xor(a1, 32);
            a2 += __shfl_xor(a2, 16); a2 += __shfl_xor(a2, 32);
            a3 += __shfl_xor(a3, 16); a3 += __shfl_xor(a3, 32);
            float inv = 1.f / (es + 1e-8f);
            gacc0 += gelu_f(a0 * inv); gacc1 += gelu_f(a1 * inv);
            gacc2 += gelu_f(a2 * inv); gacc3 += gelu_f(a3 * inv);
        }
        if (egrp == 0) {
            gred[w][fgrp * 4 + 0] = gacc0; gred[w][fgrp * 4 + 1] = gacc1;
            gred[w][fgrp * 4 + 2] = gacc2; gred[w][fgrp * 4 + 3] = gacc3;
        }
        __syncthreads();
        if (t < 64)
            atomicAdd(ws + W_GATMEAN + b * 64 + t, gred[0][t] + gred[1][t] + gred[2][t] + gred[3][t]);
        return;
    }
    // ---- dots (blocks 0..383: scheduled first, drain while GAT runs) ----
    int bb2 = blockIdx.x;
    int m = bb2 >> 7;
    int r = bb2 & 127;
    const float* mag = ws + W_MAG;
    float smx = ws[W_SMSTAT], ssm = ws[W_SMSTAT + 1];
    float sc_fw = (float)NF / ssm;
    float inv_n0 = 1.f / (sqrtf(ws[W_NORMSQ + 0]) + 1e-8f);
    float inv_n1 = 1.f / (sqrtf(ws[W_NORMSQ + 1]) + 1e-8f);
    float inv_n2 = 1.f / (sqrtf(ws[W_NORMSQ + 2]) + 1e-8f);
    float inv_n3 = 1.f / (sqrtf(ws[W_NORMSQ + 3]) + 1e-8f);
    const float* row = ((m == 0) ? fftw1 : (m == 1) ? plW : plalpha) + (size_t)r * NF;
    float a0 = 0.f, a1 = 0.f, a2 = 0.f, a3 = 0.f;
    for (int k = t; k < NF; k += 256) {
        float wv = row[k];
        float g0 = mag[k], g1 = mag[NF + k], g2 = mag[2 * NF + k], g3 = mag[3 * NF + k];
        if (m == 0) {
            float s = expf(fw[k] - smx) * sc_fw;
            wv *= s;
            a0 = fmaf(wv, g0, a0); a1 = fmaf(wv, g1, a1); a2 = fmaf(wv, g2, a2); a3 = fmaf(wv, g3, a3);
        } else if (m == 1) {
            a0 = fmaf(wv, g0, a0); a1 = fmaf(wv, g1, a1); a2 = fmaf(wv, g2, a2); a3 = fmaf(wv, g3, a3);
        } else {
            wv = 1.f / (1.f + expf(-wv));   // sigmoid(pl_alpha)
            a0 = fmaf(wv, g0 * g0 * inv_n0, a0); a1 = fmaf(wv, g1 * g1 * inv_n1, a1);
            a2 = fmaf(wv, g2 * g2 * inv_n2, a2); a3 = fmaf(wv, g3 * g3 * inv_n3, a3);
        }
    }
    __shared__ float sd[256];
    float acc[4] = {a0, a1, a2, a3};
    #pragma unroll
    for (int bb = 0; bb < 4; ++bb) {
        sd[t] = acc[bb]; __syncthreads();
        for (int o = 128; o; o >>= 1) { if (t < o) sd[t] += sd[t + o]; __syncthreads(); }
        if (t == 0) ws[W_D + ((size_t)m * 128 + r) * 4 + bb] = sd[0];
        __syncthreads();
    }
}

// ================= L6: k_final =================
DEVFN float ln64(float v, const float* g, const float* bt, int lane) {
    float mn = wred_sum(v) * (1.f / 64.f);
    float d = v - mn;
    float var = wred_sum(d * d) * (1.f / 64.f);
    return d * (1.0f / sqrtf(var + 1e-5f)) * g[lane] + bt[lane];
}
DEVFN void ln128(float& v0, float& v1, const float* g, const float* bt, int lane) {
    float mn = wred_sum(v0 + v1) * (1.f / 128.f);
    float d0 = v0 - mn, d1 = v1 - mn;
    float var = wred_sum(d0 * d0 + d1 * d1) * (1.f / 128.f);
    float rs = 1.0f / sqrtf(var + 1e-5f);
    v0 = d0 * rs * g[lane] + bt[lane];
    v1 = d1 * rs * g[lane + 64] + bt[lane + 64];
}
DEVFN float dotW128(const float* __restrict__ W, const float* __restrict__ v, int c) {
    const float4* w4 = (const float4*)(W + (size_t)c * 128);
    float acc = 0.f;
    #pragma unroll
    for (int q = 0; q < 32; ++q) {
        float4 wv = w4[q];
        const float* vv = v + q * 4;
        acc = fmaf(wv.x, vv[0], acc); acc = fmaf(wv.y, vv[1], acc);
        acc = fmaf(wv.z, vv[2], acc); acc = fmaf(wv.w, vv[3], acc);
    }
    return acc;
}
DEVFN float dotW64(const float* __restrict__ W, const float* __restrict__ v, int c) {
    const float4* w4 = (const float4*)(W + (size_t)c * 64);
    float acc = 0.f;
    #pragma unroll
    for (int q = 0; q < 16; ++q) {
        float4 wv = w4[q];
        const float* vv = v + q * 4;
        acc = fmaf(wv.x, vv[0], acc); acc = fmaf(wv.y, vv[1], acc);
        acc = fmaf(wv.z, vv[2], acc); acc = fmaf(wv.w, vv[3], acc);
    }
    return acc;
}

__global__ __launch_bounds__(256) void k_final(
    const float* __restrict__ fft_b1, const float* __restrict__ fft_ln1_g, const float* __restrict__ fft_ln1_b,
    const float* __restrict__ fft_w2, const float* __restrict__ fft_b2,
    const float* __restrict__ fft_ln2_g, const float* __restrict__ fft_ln2_b,
    const float* __restrict__ gp_w, const float* __restrict__ gp_b,
    const float* __restrict__ gp_ln_g, const float* __restrict__ gp_ln_b,
    const float* __restrict__ pl_eta, const float* __restrict__ pl_bias,
    const float* __restrict__ pn_g, const float* __restrict__ pn_b,
    const float* __restrict__ pp_w, const float* __restrict__ pp_b,
    const float* __restrict__ pp_ln_g, const float* __restrict__ pp_ln_b,
    const float* __restrict__ gate_w1, const float* __restrict__ gate_b1,
    const float* __restrict__ gate_w2, const float* __restrict__ gate_b2,
    const float* __restrict__ head_w1, const float* __restrict__ head_b1,
    const float* __restrict__ head_w2, const float* __restrict__ head_b2,
    float* __restrict__ ws, float* __restrict__ out)
{
    int t = threadIdx.x, b = t >> 6, lane = t & 63;
    __shared__ float vlds[4][256];
    float* vb = vlds[b];
    const float* D = ws + W_D;
    int r0 = lane, r1 = lane + 64;

    float f0 = D[(0 * 128 + r0) * 4 + b] + fft_b1[r0];
    float f1 = D[(0 * 128 + r1) * 4 + b] + fft_b1[r1];
    ln128(f0, f1, fft_ln1_g, fft_ln1_b, lane);
    vb[lane] = gelu_f(f0); vb[64 + lane] = gelu_f(f1);
    float catf = ln64(dotW128(fft_w2, vb, lane) + fft_b2[lane], fft_ln2_g, fft_ln2_b, lane);

    float hgm = (ws[W_H0SUM + b * 64 + lane] + ws[W_GATMEAN + b * 64 + lane]) * (1.f / N_CPGS);
    vb[lane] = hgm;
    float catg = ln64(dotW64(gp_w, vb, lane) + gp_b[lane], gp_ln_g, gp_ln_b, lane);

    float eta = pl_eta[0];
    float ys0 = D[(1 * 128 + r0) * 4 + b] + pl_bias[r0];
    float ys1 = D[(1 * 128 + r1) * 4 + b] + pl_bias[r1];
    float q0 = D[(2 * 128 + r0) * 4 + b];
    float q1 = D[(2 * 128 + r1) * 4 + b];
    float u0 = gelu_f(ys0 + eta * tanhf(ys0) * q0);
    float u1 = gelu_f(ys1 + eta * tanhf(ys1) * q1);
    ln128(u0, u1, pn_g, pn_b, lane);
    vb[lane] = u0; vb[64 + lane] = u1;
    float catp = ln64(dotW128(pp_w, vb, lane) + pp_b[lane], pp_ln_g, pp_ln_b, lane);

    vb[lane] = catf; vb[64 + lane] = catg; vb[128 + lane] = catp;
    if (lane < 6) {
        float a = gate_b1[lane];
        const float* wrow = gate_w1 + lane * 192;
        #pragma unroll 4
        for (int j = 0; j < 192; ++j) a = fmaf(wrow[j], vb[j], a);
        vb[192 + lane] = gelu_f(a);
    }
    float gv[3];
    #pragma unroll
    for (int c = 0; c < 3; ++c) {
        float a = gate_b2[c];
        #pragma unroll
        for (int j = 0; j < 6; ++j) a = fmaf(gate_w2[c * 6 + j], vb[192 + j], a);
        gv[c] = a;
    }
    float gmx = fmaxf(gv[0], fmaxf(gv[1], gv[2]));
    float e0 = expf(gv[0] - gmx), e1 = expf(gv[1] - gmx), e2 = expf(gv[2] - gmx);
    float inv = 1.f / (e0 + e1 + e2);
    float fus = catf * (e0 * inv) + catg * (e1 * inv) + catp * (e2 * inv);

    vb[lane] = fus;
    float hval = 0.f;
    if (lane < 32) {
        float a = dotW64(head_w1, vb, lane) + head_b1[lane];
        hval = gelu_f(a) * head_w2[lane];
    }
    float o = wred_sum(hval);
    if (lane == 0) out[b] = o + head_b2[0];
}

// ---------------- launch ----------------
extern "C" void kernel_launch(void* const* d_in, const int* in_sizes, int n_in,
                              void* d_out, int out_size, void* d_ws, size_t ws_size,
                              hipStream_t stream) {
    (void)in_sizes; (void)n_in; (void)out_size; (void)ws_size;
    const float* x        = (const float*)d_in[0];
    const int*   ei       = (const int*)d_in[1];
    const float* fw       = (const float*)d_in[2];
    const float* fft_w1   = (const float*)d_in[3];
    const float* fft_b1   = (const float*)d_in[4];
    const float* fft_ln1g = (const float*)d_in[5];
    const float* fft_ln1b = (const float*)d_in[6];
    const float* fft_w2   = (const float*)d_in[7];
    const float* fft_b2   = (const float*)d_in[8];
    const float* fft_ln2g = (const float*)d_in[9];
    const float* fft_ln2b = (const float*)d_in[10];
    const float* ge_w     = (const float*)d_in[11];
    const float* ge_b     = (const float*)d_in[12];
    const float* ge_g     = (const float*)d_in[13];
    const float* ge_beta  = (const float*)d_in[14];
    const float* gat_w    = (const float*)d_in[15];
    const float* gat_attn = (const float*)d_in[16];
    const float* gp_w     = (const float*)d_in[17];
    const float* gp_b     = (const float*)d_in[18];
    const float* gp_ln_g  = (const float*)d_in[19];
    const float* gp_ln_b  = (const float*)d_in[20];
    const float* pl_W     = (const float*)d_in[21];
    const float* pl_alpha = (const float*)d_in[22];
    const float* pl_eta   = (const float*)d_in[23];
    const float* pl_bias  = (const float*)d_in[24];
    const float* pn_g     = (const float*)d_in[25];
    const float* pn_b     = (const float*)d_in[26];
    const float* pp_w     = (const float*)d_in[27];
    const float* pp_b     = (const float*)d_in[28];
    const float* pp_ln_g  = (const float*)d_in[29];
    const float* pp_ln_b  = (const float*)d_in[30];
    const float* gate_w1  = (const float*)d_in[31];
    const float* gate_b1  = (const float*)d_in[32];
    const float* gate_w2  = (const float*)d_in[33];
    const float* gate_b2  = (const float*)d_in[34];
    const float* head_w1  = (const float*)d_in[35];
    const float* head_b1  = (const float*)d_in[36];
    const float* head_w2  = (const float*)d_in[37];
    const float* head_b2  = (const float*)d_in[38];

    float* ws  = (float*)d_ws;
    float* out = (float*)d_out;

    k_pre<<<26, 256, 0, stream>>>(x, ge_w, ge_b, fw, ws);
    k_node<<<4 * TILES + HB + 400, 256, 0, stream>>>(x, ge_w, ge_b, ge_g, ge_beta,
                                                     gat_w, gat_attn, ei, ws);
    k_sf2<<<81, 1024, 0, stream>>>(ws);
    k_scatmagr<<<HB + (BZ * NF + 255) / 256, 256, 0, stream>>>(ei, ws);
    k_gatdots<<<DOTSB + 2048, 256, 0, stream>>>(fft_w1, pl_W, pl_alpha, fw, ws);
    k_final<<<1, 256, 0, stream>>>(fft_b1, fft_ln1g, fft_ln1b, fft_w2, fft_b2, fft_ln2g, fft_ln2b,
                                   gp_w, gp_b, gp_ln_g, gp_ln_b, pl_eta, pl_bias, pn_g, pn_b,
                                   pp_w, pp_b, pp_ln_g, pp_ln_b, gate_w1, gate_b1, gate_w2, gate_b2,
                                   head_w1, head_b1, head_w2, head_b2, ws, out);
}

// Round 8
// 203.063 us; speedup vs baseline: 1.1133x; 1.0537x over previous
//
#include <hip/hip_runtime.h>
#include <math.h>

// ---------------- problem constants ----------------
constexpr int N_CPGS = 20000;
constexpr int NF     = 10001;      // N/2+1
constexpr int BZ     = 4;
constexpr int NEDGE  = 320000;
constexpr int KPAD   = 10240;      // padded freq count
// FFT decomposition: n = n1 + 200*n2, n1 in [0,200), n2 in [0,100)
constexpr int FN1    = 200;
constexpr int FN2    = 100;
constexpr int TILES  = (N_CPGS + 63) / 64;   // 313
constexpr int HB     = NEDGE / 256;          // 1250 hist/scatter blocks
constexpr int DOTSB  = 384;                  // dots blocks (first in k_gatdots)
constexpr int GATB   = 4096;                 // GAT blocks

// ---------------- workspace layout (float offsets) ----------------
constexpr size_t W_XMEAN   = 0;        // 4
constexpr size_t W_SMSTAT  = 64;       // 2
constexpr size_t W_NORMSQ  = 128;      // 4   [zeroed in k_pre]
constexpr size_t W_H0SUM   = 192;      // 256 [zeroed in k_pre]
constexpr size_t W_GATMEAN = 448;      // 256 [zeroed in k_pre]
constexpr size_t W_PREP    = 704;      // 8 (mw, mb, A, C, D)
constexpr size_t W_D       = 768;      // 3*128*4
constexpr size_t W_MAG     = 2304;     // BZ*NF = 40004
constexpr size_t W_SSRC    = 42368;    // float[(b*N+n)*4+h] = 320000 (per-batch)
constexpr size_t W_SDST    = 362368;   // 320000
constexpr size_t W_H       = 682368;   // bf16[(b*N+n)*64+f] = 5.12MB (per-batch)
constexpr size_t W_Y       = 5802368;  // float2[(n1*100+k2)*4+b] = 160000 floats
constexpr size_t W_COUNTS  = 9079168;  // int 20000 [zeroed via memsetAsync]
constexpr size_t W_OFFS    = 9099168;  // int 20001
constexpr size_t W_CURSOR  = 9119232;  // int 20000
constexpr size_t W_SORTSRC = 9139232;  // int 320000
// end: 9459232 floats = 37,836,928 bytes

#define DEVFN static __device__ __forceinline__

// Fast gelu: A&S 7.1.26 erf, |abs err| <= 1.5e-7.
DEVFN float gelu_f(float v) {
    float ax = fabsf(v) * 0.70710678118654752440f;
    float t = 1.0f / fmaf(0.3275911f, ax, 1.0f);
    float p = fmaf(t, 1.061405429f, -1.453152027f);
    p = fmaf(p, t, 1.421413741f);
    p = fmaf(p, t, -0.284496736f);
    p = fmaf(p, t, 0.254829592f);
    p = p * t;
    float e = __expf(-ax * ax);
    float er = copysignf(fmaf(-p, e, 1.0f), v);
    return 0.5f * v * (1.0f + er);
}

DEVFN float wred_sum(float v) {
    #pragma unroll
    for (int m = 32; m; m >>= 1) v += __shfl_xor(v, m);
    return v;
}

DEVFN unsigned int bfr(float f) {            // fp32 -> bf16 bits, RNE
    unsigned int u = __float_as_uint(f);
    return (u + 0x7fffu + ((u >> 16) & 1u)) >> 16;
}
DEVFN float bf2f(unsigned short v) { return __uint_as_float(((unsigned int)v) << 16); }

// ================= L1: k_pre — stats/zeroing (blocks 0-25) + edge histogram =================
__global__ void k_pre(const float* __restrict__ x, const float* __restrict__ ge_w,
                      const float* __restrict__ ge_b, const float* __restrict__ fw,
                      const int* __restrict__ ei, float* __restrict__ ws) {
    int bb = blockIdx.x, t = threadIdx.x;
    __shared__ float sd[256];
    if (bb >= 26) {                                    // edge histogram (counts pre-zeroed)
        int e = (bb - 26) * 256 + t;
        if (e < NEDGE) atomicAdd((int*)(ws + W_COUNTS) + ei[NEDGE + e], 1);
        return;
    }
    if (bb < 4) {
        const float4* x4 = (const float4*)(x + (size_t)bb * N_CPGS);
        float s = 0.f;
        for (int i = t; i < N_CPGS / 4; i += 256) {
            float4 v = x4[i];
            s += (v.x + v.y) + (v.z + v.w);
        }
        sd[t] = s; __syncthreads();
        for (int o = 128; o; o >>= 1) { if (t < o) sd[t] += sd[t + o]; __syncthreads(); }
        if (t == 0) ws[W_XMEAN + bb] = sd[0] * (1.0f / N_CPGS);
    } else if (bb == 4) {
        for (int i = t; i < (int)(W_PREP - W_NORMSQ); i += 256) ws[W_NORMSQ + i] = 0.f;
        if (t < 64) {
            float w = ge_w[t], b = ge_b[t];
            float mw = wred_sum(w) * (1.f / 64.f);
            float mb = wred_sum(b) * (1.f / 64.f);
            float wc = w - mw, bc = b - mb;
            float A = wred_sum(wc * wc) * (1.f / 64.f);
            float C = wred_sum(wc * bc) * (1.f / 64.f);
            float D = wred_sum(bc * bc) * (1.f / 64.f);
            if (t == 0) { float* p = ws + W_PREP; p[0] = mw; p[1] = mb; p[2] = A; p[3] = C; p[4] = D; }
        }
    } else if (bb == 5) {
        float mx = -1e30f;
        for (int i = t; i < NF; i += 256) mx = fmaxf(mx, fw[i]);
        sd[t] = mx; __syncthreads();
        for (int o = 128; o; o >>= 1) { if (t < o) sd[t] = fmaxf(sd[t], sd[t + o]); __syncthreads(); }
        mx = sd[0]; __syncthreads();
        float s = 0.f;
        for (int i = t; i < NF; i += 256) s += expf(fw[i] - mx);
        sd[t] = s; __syncthreads();
        for (int o = 128; o; o >>= 1) { if (t < o) sd[t] += sd[t + o]; __syncthreads(); }
        if (t == 0) { ws[W_SMSTAT] = mx; ws[W_SMSTAT + 1] = sd[0]; }
    }
    // blocks 6..25: idle (kept for dispatch simplicity)
}

// ====== L2: k_node — block 0: scan; [1,1+4*TILES): node tiles; rest: FFT stage 1 ======
__global__ __launch_bounds__(256) void k_node(
    const float* __restrict__ x, const float* __restrict__ ge_w, const float* __restrict__ ge_b,
    const float* __restrict__ ge_g, const float* __restrict__ ge_beta,
    const float* __restrict__ gat_w, const float* __restrict__ gat_attn,
    float* __restrict__ ws)
{
    int t = threadIdx.x;
    int nb = blockIdx.x;
    if (nb == 0) {                                     // exclusive scan of dst counts (256 thr)
        const int* cnt = (const int*)(ws + W_COUNTS);
        int* offs = (int*)(ws + W_OFFS);
        int* cur  = (int*)(ws + W_CURSOR);
        constexpr int PER = (N_CPGS + 255) / 256;      // 79
        int i0 = t * PER;
        int s = 0;
        for (int i = 0; i < PER; ++i) { int idx = i0 + i; if (idx < N_CPGS) s += cnt[idx]; }
        __shared__ int sdi[256];
        sdi[t] = s; __syncthreads();
        for (int off = 1; off < 256; off <<= 1) {
            int v = (t >= off) ? sdi[t - off] : 0;
            __syncthreads();
            sdi[t] += v;
            __syncthreads();
        }
        int run = sdi[t] - s;
        for (int i = 0; i < PER; ++i) {
            int idx = i0 + i;
            if (idx < N_CPGS) { offs[idx] = run; cur[idx] = run; run += cnt[idx]; }
        }
        if (t == 255) offs[N_CPGS] = sdi[255];
        return;
    }
    if (nb >= 1 + 4 * TILES) {                         // FFT stage 1
        int fb = nb - 1 - 4 * TILES;                   // 0..399
        int b = fb / 100;
        int n1base = (fb % 100) * 2;
        int n1l = t >> 7, k2 = t & 127;
        __shared__ float xs[2][100];
        float xm = ws[W_XMEAN + b];
        for (int i = t; i < 200; i += 256) {
            int nl = (i >= 100) ? 1 : 0, n2 = (i >= 100) ? i - 100 : i;
            xs[nl][n2] = x[(size_t)b * N_CPGS + n1base + nl + 200 * n2] - xm;
        }
        __syncthreads();
        int k2e = (k2 < 100) ? k2 : 0;
        constexpr float T100 = 6.2831853071795864769f / 100.f;
        float dc, dsn;
        { float sn, cn; sincosf(T100 * (float)k2e, &sn, &cn); dc = cn; dsn = -sn; }
        float yr = 0.f, yi = 0.f;
        #pragma unroll
        for (int half = 0; half < 2; ++half) {
            float c, s;
            { int m = (k2e * (half * 50)) % 100; float sn, cn; sincosf(T100 * (float)m, &sn, &cn); c = cn; s = -sn; }
            #pragma unroll 5
            for (int j = 0; j < 50; ++j) {
                float xv = xs[n1l][half * 50 + j];
                yr = fmaf(xv, c, yr); yi = fmaf(xv, s, yi);
                float tc_ = c * dc - s * dsn; s = s * dc + c * dsn; c = tc_;
            }
        }
        if (k2 < 100)
            ((float2*)(ws + W_Y))[((size_t)(n1base + n1l) * FN2 + k2) * 4 + b] = make_float2(yr, yi);
        return;
    }
    int nb2 = nb - 1;
    int b = nb2 / TILES;
    int tile = nb2 % TILES;
    int n0 = tile * 64;

    __shared__ __align__(16) float h0T[64 * 68];   // [feat j][node]
    __shared__ __align__(16) float gwT[64 * 68];   // [j][i] = gat_w[i][j]
    __shared__ float xsv[64], rss[64];

    const float* prep = ws + W_PREP;
    float mw = prep[0], mb = prep[1], A = prep[2], C = prep[3], Dd = prep[4];

    for (int idx = t; idx < 4096; idx += 256) { int i = idx >> 6, j = idx & 63; gwT[j * 68 + i] = gat_w[idx]; }
    if (t < 64) {
        int n = n0 + t;
        float xv = (n < N_CPGS) ? x[(size_t)b * N_CPGS + n] : 0.f;
        xsv[t] = xv;
        float var = xv * xv * A + 2.f * xv * C + Dd;
        rss[t] = 1.0f / sqrtf(var + 1e-5f);
    }
    __syncthreads();

    for (int idx = t; idx < 4096; idx += 256) {
        int j = idx >> 6, nd = idx & 63;
        float h0 = 0.f;
        if (n0 + nd < N_CPGS) {
            float v = (xsv[nd] * (ge_w[j] - mw) + (ge_b[j] - mb)) * rss[nd];
            h0 = gelu_f(v * ge_g[j] + ge_beta[j]);
        }
        h0T[j * 68 + nd] = h0;
    }
    __syncthreads();

    // 64x64 @ 64x64 matmul, 16x16 threads, 4x4 micro-tile
    int tr = t >> 4, tc = t & 15;
    float acc[4][4] = {};
    #pragma unroll 8
    for (int j = 0; j < 64; ++j) {
        const float4 av = *(const float4*)&h0T[j * 68 + (tr << 2)];
        const float4 bv = *(const float4*)&gwT[j * 68 + (tc << 2)];
        #pragma unroll
        for (int u = 0; u < 4; ++u) {
            float a = (u == 0) ? av.x : (u == 1) ? av.y : (u == 2) ? av.z : av.w;
            acc[u][0] = fmaf(a, bv.x, acc[u][0]);
            acc[u][1] = fmaf(a, bv.y, acc[u][1]);
            acc[u][2] = fmaf(a, bv.z, acc[u][2]);
            acc[u][3] = fmaf(a, bv.w, acc[u][3]);
        }
    }
    // h0 feature sums
    if (t < 64) {
        float s = 0.f;
        #pragma unroll 8
        for (int nd = 0; nd < 64; ++nd) s += h0T[t * 68 + nd];
        atomicAdd(ws + W_H0SUM + b * 64 + t, s);
    }
    // h write (bf16, per-batch layout)
    unsigned short* hbp = (unsigned short*)(ws + W_H);
    #pragma unroll
    for (int u = 0; u < 4; ++u) {
        int n = n0 + tr * 4 + u;
        if (n < N_CPGS) {
            unsigned int lo = bfr(acc[u][0]) | (bfr(acc[u][1]) << 16);
            unsigned int hi = bfr(acc[u][2]) | (bfr(acc[u][3]) << 16);
            *(uint2*)(hbp + ((size_t)b * N_CPGS + n) * 64 + tc * 4) = make_uint2(lo, hi);
        }
    }
    // attention scores straight from registers
    {
        int hh = tc >> 2;
        float ps[4], pd[4];
        #pragma unroll
        for (int u = 0; u < 4; ++u) {
            float s = 0.f, d = 0.f;
            #pragma unroll
            for (int kk = 0; kk < 4; ++kk) {
                float asv = gat_attn[hh * 32 + (tc & 3) * 4 + kk];
                float adv = gat_attn[hh * 32 + 16 + (tc & 3) * 4 + kk];
                s = fmaf(acc[u][kk], asv, s);
                d = fmaf(acc[u][kk], adv, d);
            }
            ps[u] = s; pd[u] = d;
        }
        #pragma unroll
        for (int u = 0; u < 4; ++u) {
            ps[u] += __shfl_xor(ps[u], 1); ps[u] += __shfl_xor(ps[u], 2);
            pd[u] += __shfl_xor(pd[u], 1); pd[u] += __shfl_xor(pd[u], 2);
        }
        if ((tc & 3) == 0) {
            #pragma unroll
            for (int u = 0; u < 4; ++u) {
                int n = n0 + tr * 4 + u;
                if (n < N_CPGS) {
                    ws[W_SSRC + ((size_t)b * N_CPGS + n) * 4 + hh] = ps[u];
                    ws[W_SDST + ((size_t)b * N_CPGS + n) * 4 + hh] = pd[u];
                }
            }
        }
    }
}

// ====== L3: k_scat2 — [0,HB): edge scatter; [HB,HB+160): full FFT stage 2 + mag + norms ====
__global__ __launch_bounds__(256) void k_scat2(const int* __restrict__ ei,
                                               float* __restrict__ ws) {
    int t = threadIdx.x;
    if (blockIdx.x < HB) {
        int e = blockIdx.x * 256 + t;
        if (e < NEDGE) {
            int s = ei[e], d = ei[NEDGE + e];
            int pos = atomicAdd((int*)(ws + W_CURSOR) + d, 1);
            ((int*)(ws + W_SORTSRC))[pos] = s;
        }
        return;
    }
    // FFT stage 2, full 200-term sum per thread: gid -> (k, b)
    int gid = (blockIdx.x - HB) * 256 + t;             // 0..40959
    int k = gid >> 2, b = gid & 3;                     // k < KPAD
    int k2 = k % 100;
    const float2* Y2 = (const float2*)(ws + W_Y);
    constexpr float W0 = 6.2831853071795864769f / 20000.f;
    float dc, dsn;
    { float sn, cn; sincosf(W0 * (float)k, &sn, &cn); dc = cn; dsn = -sn; }
    float xr = 0.f, xi = 0.f;
    #pragma unroll
    for (int seg = 0; seg < 4; ++seg) {
        int n1b = seg * 50;
        float c, s;
        { int m = (k * n1b) % 20000; float sn, cn; sincosf(W0 * (float)m, &sn, &cn); c = cn; s = -sn; }
        #pragma unroll 5
        for (int j = 0; j < 50; ++j) {
            float2 y = Y2[((size_t)(n1b + j) * FN2 + k2) * 4 + b];
            xr = fmaf(y.x, c, xr); xr = fmaf(-y.y, s, xr);
            xi = fmaf(y.x, s, xi); xi = fmaf( y.y, c, xi);
            float tc_ = c * dc - s * dsn; s = s * dc + c * dsn; c = tc_;
        }
    }
    bool ok = k < NF;
    float m = 0.f;
    if (ok) {
        m = log1pf(sqrtf(xr * xr + xi * xi));
        ws[W_MAG + (size_t)b * NF + k] = m;
    }
    float msq = ok ? m * m : 0.f;
    #pragma unroll
    for (int o = 4; o < 64; o <<= 1) msq += __shfl_xor(msq, o);   // sum over same-b lanes
    if ((t & 63) < 4) atomicAdd(ws + W_NORMSQ + b, msq);
}

// ======== L4: k_gatdots — [0,DOTSB): dots; [DOTSB,DOTSB+GATB): GAT ====
__global__ __launch_bounds__(256) void k_gatdots(
    const float* __restrict__ fftw1, const float* __restrict__ plW,
    const float* __restrict__ plalpha, const float* __restrict__ fw,
    float* __restrict__ ws)
{
    int t = threadIdx.x;
    if (blockIdx.x >= DOTSB) {
        // ---- GAT: per-batch blocks, XCD swizzle, single-pass softmax, uint2 bf16 gather ----
        int g = blockIdx.x - DOTSB;                    // 0..4095
        int xcd = g & 7;
        int b = xcd >> 1;                              // batch pinned to 2 XCDs
        int blk = ((g >> 3) << 1) | (xcd & 1);         // 0..1023
        int w = t >> 6, lane = t & 63;
        int wv = blk * 4 + w;                          // 0..4095
        int egrp = lane >> 4, fgrp = lane & 15;
        int hh = fgrp >> 2;
        const int* offs = (const int*)(ws + W_OFFS);
        const int* ssrt = (const int*)(ws + W_SORTSRC);
        const float4* s4src = (const float4*)(ws + W_SSRC);
        const float4* s4dst = (const float4*)(ws + W_SDST);
        const uint2* hbp = (const uint2*)(ws + W_H);
        size_t bN = (size_t)b * N_CPGS;
        float gacc0 = 0.f, gacc1 = 0.f, gacc2 = 0.f, gacc3 = 0.f;

        __shared__ float elds[4][4][68];               // [wave][head][edge]
        __shared__ int   slds[4][68];
        __shared__ float gred[4][64];

        for (int dst = wv; dst < N_CPGS; dst += GATB) {
            int o0 = offs[dst], o1 = offs[dst + 1];
            if (o0 == o1) continue;                    // gelu(0) = 0
            float4 sd4 = s4dst[bN + dst];
            float es = 0.f;
            float a0 = 0.f, a1 = 0.f, a2 = 0.f, a3 = 0.f;
            for (int c0 = o0; c0 < o1; c0 += 64) {
                int cnt = min(64, o1 - c0);
                float v0 = 0.f, v1 = 0.f, v2 = 0.f, v3 = 0.f;
                int s = 0;
                if (lane < cnt) {
                    s = ssrt[c0 + lane];
                    float4 ss = s4src[bN + s];
                    v0 = ss.x + sd4.x; v0 = (v0 >= 0.f) ? v0 : 0.2f * v0; v0 = __expf(v0);
                    v1 = ss.y + sd4.y; v1 = (v1 >= 0.f) ? v1 : 0.2f * v1; v1 = __expf(v1);
                    v2 = ss.z + sd4.z; v2 = (v2 >= 0.f) ? v2 : 0.2f * v2; v2 = __expf(v2);
                    v3 = ss.w + sd4.w; v3 = (v3 >= 0.f) ? v3 : 0.2f * v3; v3 = __expf(v3);
                }
                slds[w][lane] = s;
                elds[w][0][lane] = v0; elds[w][1][lane] = v1;
                elds[w][2][lane] = v2; elds[w][3][lane] = v3;
                int niter = (cnt + 3) >> 2;
                for (int i = 0; i < niter; ++i) {
                    int j = (i << 2) + egrp;
                    float e = elds[w][hh][j];
                    int sj = slds[w][j];
                    uint2 hv = hbp[(bN + sj) * 16 + fgrp];
                    es += e;
                    a0 = fmaf(e, bf2f((unsigned short)(hv.x & 0xffffu)), a0);
                    a1 = fmaf(e, bf2f((unsigned short)(hv.x >> 16)),     a1);
                    a2 = fmaf(e, bf2f((unsigned short)(hv.y & 0xffffu)), a2);
                    a3 = fmaf(e, bf2f((unsigned short)(hv.y >> 16)),     a3);
                }
            }
            es += __shfl_xor(es, 16); es += __shfl_xor(es, 32);
            a0 += __shfl_xor(a0, 16); a0 += __shfl_xor(a0, 32);
            a1 += __shfl_xor(a1, 16); a1 += __shfl_xor(a1, 32);
            a2 += __shfl_xor(a2, 16); a2 += __shfl_xor(a2, 32);
            a3 += __shfl_xor(a3, 16); a3 += __shfl_xor(a3, 32);
            float inv = 1.f / (es + 1e-8f);
            gacc0 += gelu_f(a0 * inv); gacc1 += gelu_f(a1 * inv);
            gacc2 += gelu_f(a2 * inv); gacc3 += gelu_f(a3 * inv);
        }
        if (egrp == 0) {
            gred[w][fgrp * 4 + 0] = gacc0; gred[w][fgrp * 4 + 1] = gacc1;
            gred[w][fgrp * 4 + 2] = gacc2; gred[w][fgrp * 4 + 3] = gacc3;
        }
        __syncthreads();
        if (t < 64)
            atomicAdd(ws + W_GATMEAN + b * 64 + t, gred[0][t] + gred[1][t] + gred[2][t] + gred[3][t]);
        return;
    }
    // ---- dots (blocks 0..383) ----
    int bb2 = blockIdx.x;
    int m = bb2 >> 7;
    int r = bb2 & 127;
    const float* mag = ws + W_MAG;
    float smx = ws[W_SMSTAT], ssm = ws[W_SMSTAT + 1];
    float sc_fw = (float)NF / ssm;
    float inv_n0 = 1.f / (sqrtf(ws[W_NORMSQ + 0]) + 1e-8f);
    float inv_n1 = 1.f / (sqrtf(ws[W_NORMSQ + 1]) + 1e-8f);
    float inv_n2 = 1.f / (sqrtf(ws[W_NORMSQ + 2]) + 1e-8f);
    float inv_n3 = 1.f / (sqrtf(ws[W_NORMSQ + 3]) + 1e-8f);
    const float* row = ((m == 0) ? fftw1 : (m == 1) ? plW : plalpha) + (size_t)r * NF;
    float a0 = 0.f, a1 = 0.f, a2 = 0.f, a3 = 0.f;
    for (int k = t; k < NF; k += 256) {
        float wv = row[k];
        float g0 = mag[k], g1 = mag[NF + k], g2 = mag[2 * NF + k], g3 = mag[3 * NF + k];
        if (m == 0) {
            float s = expf(fw[k] - smx) * sc_fw;
            wv *= s;
            a0 = fmaf(wv, g0, a0); a1 = fmaf(wv, g1, a1); a2 = fmaf(wv, g2, a2); a3 = fmaf(wv, g3, a3);
        } else if (m == 1) {
            a0 = fmaf(wv, g0, a0); a1 = fmaf(wv, g1, a1); a2 = fmaf(wv, g2, a2); a3 = fmaf(wv, g3, a3);
        } else {
            wv = 1.f / (1.f + expf(-wv));   // sigmoid(pl_alpha)
            a0 = fmaf(wv, g0 * g0 * inv_n0, a0); a1 = fmaf(wv, g1 * g1 * inv_n1, a1);
            a2 = fmaf(wv, g2 * g2 * inv_n2, a2); a3 = fmaf(wv, g3 * g3 * inv_n3, a3);
        }
    }
    __shared__ float sd[256];
    float acc[4] = {a0, a1, a2, a3};
    #pragma unroll
    for (int bb = 0; bb < 4; ++bb) {
        sd[t] = acc[bb]; __syncthreads();
        for (int o = 128; o; o >>= 1) { if (t < o) sd[t] += sd[t + o]; __syncthreads(); }
        if (t == 0) ws[W_D + ((size_t)m * 128 + r) * 4 + bb] = sd[0];
        __syncthreads();
    }
}

// ================= L5: k_final =================
DEVFN float ln64(float v, const float* g, const float* bt, int lane) {
    float mn = wred_sum(v) * (1.f / 64.f);
    float d = v - mn;
    float var = wred_sum(d * d) * (1.f / 64.f);
    return d * (1.0f / sqrtf(var + 1e-5f)) * g[lane] + bt[lane];
}
DEVFN void ln128(float& v0, float& v1, const float* g, const float* bt, int lane) {
    float mn = wred_sum(v0 + v1) * (1.f / 128.f);
    float d0 = v0 - mn, d1 = v1 - mn;
    float var = wred_sum(d0 * d0 + d1 * d1) * (1.f / 128.f);
    float rs = 1.0f / sqrtf(var + 1e-5f);
    v0 = d0 * rs * g[lane] + bt[lane];
    v1 = d1 * rs * g[lane + 64] + bt[lane + 64];
}
DEVFN float dotW128(const float* __restrict__ W, const float* __restrict__ v, int c) {
    const float4* w4 = (const float4*)(W + (size_t)c * 128);
    float acc = 0.f;
    #pragma unroll
    for (int q = 0; q < 32; ++q) {
        float4 wv = w4[q];
        const float* vv = v + q * 4;
        acc = fmaf(wv.x, vv[0], acc); acc = fmaf(wv.y, vv[1], acc);
        acc = fmaf(wv.z, vv[2], acc); acc = fmaf(wv.w, vv[3], acc);
    }
    return acc;
}
DEVFN float dotW64(const float* __restrict__ W, const float* __restrict__ v, int c) {
    const float4* w4 = (const float4*)(W + (size_t)c * 64);
    float acc = 0.f;
    #pragma unroll
    for (int q = 0; q < 16; ++q) {
        float4 wv = w4[q];
        const float* vv = v + q * 4;
        acc = fmaf(wv.x, vv[0], acc); acc = fmaf(wv.y, vv[1], acc);
        acc = fmaf(wv.z, vv[2], acc); acc = fmaf(wv.w, vv[3], acc);
    }
    return acc;
}

__global__ __launch_bounds__(256) void k_final(
    const float* __restrict__ fft_b1, const float* __restrict__ fft_ln1_g, const float* __restrict__ fft_ln1_b,
    const float* __restrict__ fft_w2, const float* __restrict__ fft_b2,
    const float* __restrict__ fft_ln2_g, const float* __restrict__ fft_ln2_b,
    const float* __restrict__ gp_w, const float* __restrict__ gp_b,
    const float* __restrict__ gp_ln_g, const float* __restrict__ gp_ln_b,
    const float* __restrict__ pl_eta, const float* __restrict__ pl_bias,
    const float* __restrict__ pn_g, const float* __restrict__ pn_b,
    const float* __restrict__ pp_w, const float* __restrict__ pp_b,
    const float* __restrict__ pp_ln_g, const float* __restrict__ pp_ln_b,
    const float* __restrict__ gate_w1, const float* __restrict__ gate_b1,
    const float* __restrict__ gate_w2, const float* __restrict__ gate_b2,
    const float* __restrict__ head_w1, const float* __restrict__ head_b1,
    const float* __restrict__ head_w2, const float* __restrict__ head_b2,
    float* __restrict__ ws, float* __restrict__ out)
{
    int t = threadIdx.x, b = t >> 6, lane = t & 63;
    __shared__ float vlds[4][256];
    float* vb = vlds[b];
    const float* D = ws + W_D;
    int r0 = lane, r1 = lane + 64;

    float f0 = D[(0 * 128 + r0) * 4 + b] + fft_b1[r0];
    float f1 = D[(0 * 128 + r1) * 4 + b] + fft_b1[r1];
    ln128(f0, f1, fft_ln1_g, fft_ln1_b, lane);
    vb[lane] = gelu_f(f0); vb[64 + lane] = gelu_f(f1);
    float catf = ln64(dotW128(fft_w2, vb, lane) + fft_b2[lane], fft_ln2_g, fft_ln2_b, lane);

    float hgm = (ws[W_H0SUM + b * 64 + lane] + ws[W_GATMEAN + b * 64 + lane]) * (1.f / N_CPGS);
    vb[lane] = hgm;
    float catg = ln64(dotW64(gp_w, vb, lane) + gp_b[lane], gp_ln_g, gp_ln_b, lane);

    float eta = pl_eta[0];
    float ys0 = D[(1 * 128 + r0) * 4 + b] + pl_bias[r0];
    float ys1 = D[(1 * 128 + r1) * 4 + b] + pl_bias[r1];
    float q0 = D[(2 * 128 + r0) * 4 + b];
    float q1 = D[(2 * 128 + r1) * 4 + b];
    float u0 = gelu_f(ys0 + eta * tanhf(ys0) * q0);
    float u1 = gelu_f(ys1 + eta * tanhf(ys1) * q1);
    ln128(u0, u1, pn_g, pn_b, lane);
    vb[lane] = u0; vb[64 + lane] = u1;
    float catp = ln64(dotW128(pp_w, vb, lane) + pp_b[lane], pp_ln_g, pp_ln_b, lane);

    vb[lane] = catf; vb[64 + lane] = catg; vb[128 + lane] = catp;
    if (lane < 6) {
        float a = gate_b1[lane];
        const float* wrow = gate_w1 + lane * 192;
        #pragma unroll 4
        for (int j = 0; j < 192; ++j) a = fmaf(wrow[j], vb[j], a);
        vb[192 + lane] = gelu_f(a);
    }
    float gv[3];
    #pragma unroll
    for (int c = 0; c < 3; ++c) {
        float a = gate_b2[c];
        #pragma unroll
        for (int j = 0; j < 6; ++j) a = fmaf(gate_w2[c * 6 + j], vb[192 + j], a);
        gv[c] = a;
    }
    float gmx = fmaxf(gv[0], fmaxf(gv[1], gv[2]));
    float e0 = expf(gv[0] - gmx), e1 = expf(gv[1] - gmx), e2 = expf(gv[2] - gmx);
    float inv = 1.f / (e0 + e1 + e2);
    float fus = catf * (e0 * inv) + catg * (e1 * inv) + catp * (e2 * inv);

    vb[lane] = fus;
    float hval = 0.f;
    if (lane < 32) {
        float a = dotW64(head_w1, vb, lane) + head_b1[lane];
        hval = gelu_f(a) * head_w2[lane];
    }
    float o = wred_sum(hval);
    if (lane == 0) out[b] = o + head_b2[0];
}

// ---------------- launch ----------------
extern "C" void kernel_launch(void* const* d_in, const int* in_sizes, int n_in,
                              void* d_out, int out_size, void* d_ws, size_t ws_size,
                              hipStream_t stream) {
    (void)in_sizes; (void)n_in; (void)out_size; (void)ws_size;
    const float* x        = (const float*)d_in[0];
    const int*   ei       = (const int*)d_in[1];
    const float* fw       = (const float*)d_in[2];
    const float* fft_w1   = (const float*)d_in[3];
    const float* fft_b1   = (const float*)d_in[4];
    const float* fft_ln1g = (const float*)d_in[5];
    const float* fft_ln1b = (const float*)d_in[6];
    const float* fft_w2   = (const float*)d_in[7];
    const float* fft_b2   = (const float*)d_in[8];
    const float* fft_ln2g = (const float*)d_in[9];
    const float* fft_ln2b = (const float*)d_in[10];
    const float* ge_w     = (const float*)d_in[11];
    const float* ge_b     = (const float*)d_in[12];
    const float* ge_g     = (const float*)d_in[13];
    const float* ge_beta  = (const float*)d_in[14];
    const float* gat_w    = (const float*)d_in[15];
    const float* gat_attn = (const float*)d_in[16];
    const float* gp_w     = (const float*)d_in[17];
    const float* gp_b     = (const float*)d_in[18];
    const float* gp_ln_g  = (const float*)d_in[19];
    const float* gp_ln_b  = (const float*)d_in[20];
    const float* pl_W     = (const float*)d_in[21];
    const float* pl_alpha = (const float*)d_in[22];
    const float* pl_eta   = (const float*)d_in[23];
    const float* pl_bias  = (const float*)d_in[24];
    const float* pn_g     = (const float*)d_in[25];
    const float* pn_b     = (const float*)d_in[26];
    const float* pp_w     = (const float*)d_in[27];
    const float* pp_b     = (const float*)d_in[28];
    const float* pp_ln_g  = (const float*)d_in[29];
    const float* pp_ln_b  = (const float*)d_in[30];
    const float* gate_w1  = (const float*)d_in[31];
    const float* gate_b1  = (const float*)d_in[32];
    const float* gate_w2  = (const float*)d_in[33];
    const float* gate_b2  = (const float*)d_in[34];
    const float* head_w1  = (const float*)d_in[35];
    const float* head_b1  = (const float*)d_in[36];
    const float* head_w2  = (const float*)d_in[37];
    const float* head_b2  = (const float*)d_in[38];

    float* ws  = (float*)d_ws;
    float* out = (float*)d_out;

    hipMemsetAsync(ws + W_COUNTS, 0, N_CPGS * sizeof(int), stream);
    k_pre<<<26 + HB, 256, 0, stream>>>(x, ge_w, ge_b, fw, ei, ws);
    k_node<<<1 + 4 * TILES + 400, 256, 0, stream>>>(x, ge_w, ge_b, ge_g, ge_beta,
                                                    gat_w, gat_attn, ws);
    k_scat2<<<HB + 160, 256, 0, stream>>>(ei, ws);
    k_gatdots<<<DOTSB + GATB, 256, 0, stream>>>(fft_w1, pl_W, pl_alpha, fw, ws);
    k_final<<<1, 256, 0, stream>>>(fft_b1, fft_ln1g, fft_ln1b, fft_w2, fft_b2, fft_ln2g, fft_ln2b,
                                   gp_w, gp_b, gp_ln_g, gp_ln_b, pl_eta, pl_bias, pn_g, pn_b,
                                   pp_w, pp_b, pp_ln_g, pp_ln_b, gate_w1, gate_b1, gate_w2, gate_b2,
                                   head_w1, head_b1, head_w2, head_b2, ws, out);
}